// Round 1
// baseline (366.059 us; speedup 1.0000x reference)
//
#include <hip/hip_runtime.h>
#include <hip/hip_bf16.h>
#include <math.h>

typedef unsigned short u16;
typedef __attribute__((ext_vector_type(4))) float f32x4;
typedef __attribute__((ext_vector_type(8))) short s16x8;

#define B_    8
#define N_    4096
#define DIM_  512
#define TOK   32768     // B_*N_
#define QKVD  1536

__device__ __forceinline__ float bf2f(u16 u) {
    union { unsigned int i; float f; } x; x.i = ((unsigned int)u) << 16; return x.f;
}
__device__ __forceinline__ u16 f2bf(float f) {
    union { float f; unsigned int i; } x; x.f = f;
    unsigned int r = (x.i + 0x7fffu + ((x.i >> 16) & 1u)) >> 16;
    return (u16)r;
}

__device__ __forceinline__ void gload_lds16(const void* g, void* l) {
    __builtin_amdgcn_global_load_lds(
        (const __attribute__((address_space(1))) unsigned int*)g,
        (__attribute__((address_space(3))) unsigned int*)l, 16, 0, 0);
}

// ---------------- conditioning affine: cond[b][j] = silu(ce[b]) . w_cond[j] + b_cond[j]
__global__ void k_cond(const float* __restrict__ ce, const float* __restrict__ w_cond,
                       const float* __restrict__ b_cond, float* __restrict__ cond)
{
    __shared__ float s[512];
    int b = blockIdx.x, tid = threadIdx.x;
    for (int i = tid; i < 512; i += 256) {
        float v = ce[b * 512 + i];
        s[i] = v / (1.f + expf(-v));
    }
    __syncthreads();
    const float4* w4 = (const float4*)w_cond;
    for (int j = tid; j < 1024; j += 256) {
        float acc = b_cond[j];
#pragma unroll 4
        for (int i4 = 0; i4 < 128; ++i4) {
            float4 w = w4[j * 128 + i4];
            acc += s[i4*4+0]*w.x + s[i4*4+1]*w.y + s[i4*4+2]*w.z + s[i4*4+3]*w.w;
        }
        cond[b * 1024 + j] = acc;
    }
}

// ---------------- w_qkv fp32 -> bf16
__global__ void k_w2bf(const float* __restrict__ w, u16* __restrict__ wb)
{
    int i = (blockIdx.x * 256 + threadIdx.x) * 4;
    float4 v = *(const float4*)&w[i];
    ushort4 o; o.x = f2bf(v.x); o.y = f2bf(v.y); o.z = f2bf(v.z); o.w = f2bf(v.w);
    *(ushort4*)&wb[i] = o;
}

// ---------------- pre-LN + modulation -> xm bf16 ; one wave per token
__global__ void k_lnmod(const float* __restrict__ x, const float* __restrict__ cond,
                        const float* __restrict__ gamma, u16* __restrict__ xm)
{
    int wave = threadIdx.x >> 6, lane = threadIdx.x & 63;
    size_t t = (size_t)blockIdx.x * 4 + wave;
    const float* xr = x + t * 512;
    float4 v0 = ((const float4*)xr)[lane * 2];
    float4 v1 = ((const float4*)xr)[lane * 2 + 1];
    float s  = v0.x+v0.y+v0.z+v0.w + v1.x+v1.y+v1.z+v1.w;
    float ss = v0.x*v0.x+v0.y*v0.y+v0.z*v0.z+v0.w*v0.w
             + v1.x*v1.x+v1.y*v1.y+v1.z*v1.z+v1.w*v1.w;
#pragma unroll
    for (int m = 1; m < 64; m <<= 1) { s += __shfl_xor(s, m, 64); ss += __shfl_xor(ss, m, 64); }
    float mu = s * (1.f/512.f);
    float var = ss * (1.f/512.f) - mu * mu;
    float rs = rsqrtf(var + 1e-5f);
    int b = (int)(t >> 12);
    const float* cb = cond + b * 1024;
    float4 g0  = ((const float4*)gamma)[lane*2],     g1  = ((const float4*)gamma)[lane*2+1];
    float4 sc0 = ((const float4*)cb)[lane*2],        sc1 = ((const float4*)cb)[lane*2+1];
    float4 sh0 = ((const float4*)(cb+512))[lane*2],  sh1 = ((const float4*)(cb+512))[lane*2+1];
    ushort4 o0, o1;
    o0.x = f2bf(((v0.x-mu)*rs*g0.x)*(1.f+sc0.x) + sh0.x);
    o0.y = f2bf(((v0.y-mu)*rs*g0.y)*(1.f+sc0.y) + sh0.y);
    o0.z = f2bf(((v0.z-mu)*rs*g0.z)*(1.f+sc0.z) + sh0.z);
    o0.w = f2bf(((v0.w-mu)*rs*g0.w)*(1.f+sc0.w) + sh0.w);
    o1.x = f2bf(((v1.x-mu)*rs*g1.x)*(1.f+sc1.x) + sh1.x);
    o1.y = f2bf(((v1.y-mu)*rs*g1.y)*(1.f+sc1.y) + sh1.y);
    o1.z = f2bf(((v1.z-mu)*rs*g1.z)*(1.f+sc1.z) + sh1.z);
    o1.w = f2bf(((v1.w-mu)*rs*g1.w)*(1.f+sc1.w) + sh1.w);
    ushort4* orow = (ushort4*)(xm + t * 512);
    orow[lane * 2] = o0; orow[lane * 2 + 1] = o1;
}

// ---------------- bf16 MFMA GEMM: Out[m][n] = sum_k A[m][k] * Bm[n][k]
// 128x128 tile, BK=32, 4 waves (2x2), 16x16x32 bf16 MFMA. K fixed = 512.
// Bm is "B^T input" (row-major [ncols][512]); per-batch B offset via perBatchB.
template<int OUT_BF16>
__global__ __launch_bounds__(256, 2)
void k_gemm(const u16* __restrict__ A, int lda,
            const u16* __restrict__ Bm, int perBatchB,
            void* __restrict__ Out, int ldo, int ntiles)
{
    __shared__ __align__(16) u16 As[128 * 32];
    __shared__ __align__(16) u16 Bs[128 * 32];
    int bid = blockIdx.x;
    int bn = bid % ntiles, bm = bid / ntiles;
    int m0 = bm * 128, n0 = bn * 128;
    const u16* Bp = Bm + (size_t)(m0 >> 12) * perBatchB;
    int tid = threadIdx.x;
    int wid = tid >> 6, lane = tid & 63;
    int wr = (wid >> 1) * 64, wc = (wid & 1) * 64;
    int fr = lane & 15, fk = (lane >> 4) * 8;

    f32x4 acc[4][4];
#pragma unroll
    for (int m = 0; m < 4; ++m)
#pragma unroll
        for (int n = 0; n < 4; ++n) acc[m][n] = (f32x4)0.f;

    for (int k0 = 0; k0 < 512; k0 += 32) {
#pragma unroll
        for (int i = 0; i < 2; ++i) {
            int chunk = tid + i * 256;
            int row = chunk >> 2, part = chunk & 3;
            gload_lds16(A  + (size_t)(m0 + row) * lda + k0 + part * 8, &As[chunk * 8]);
            gload_lds16(Bp + (size_t)(n0 + row) * 512 + k0 + part * 8, &Bs[chunk * 8]);
        }
        __syncthreads();
        s16x8 af[4], bfr[4];
#pragma unroll
        for (int m = 0; m < 4; ++m) af[m]  = *(const s16x8*)&As[(wr + m*16 + fr) * 32 + fk];
#pragma unroll
        for (int n = 0; n < 4; ++n) bfr[n] = *(const s16x8*)&Bs[(wc + n*16 + fr) * 32 + fk];
#pragma unroll
        for (int m = 0; m < 4; ++m)
#pragma unroll
            for (int n = 0; n < 4; ++n)
                acc[m][n] = __builtin_amdgcn_mfma_f32_16x16x32_bf16(af[m], bfr[n], acc[m][n], 0, 0, 0);
        __syncthreads();
    }

    int rbase = m0 + wr + (lane >> 4) * 4;
    int cbase = n0 + wc + (lane & 15);
#pragma unroll
    for (int m = 0; m < 4; ++m)
#pragma unroll
        for (int n = 0; n < 4; ++n)
#pragma unroll
            for (int r = 0; r < 4; ++r) {
                size_t idx = (size_t)(rbase + m*16 + r) * ldo + (cbase + n*16);
                float v = acc[m][n][r];
                if (OUT_BF16) ((u16*)Out)[idx] = f2bf(v);
                else          ((float*)Out)[idx] = v;
            }
}

// ---------------- k column stats (softmax over sequence dim), stage 1: partials
__global__ void k_kstat1(const u16* __restrict__ qkv, float* __restrict__ pmax, float* __restrict__ psum)
{
    __shared__ float ms[4][64], ss_[4][64];
    int rc = blockIdx.x, ct = blockIdx.y, b = blockIdx.z;
    int tid = threadIdx.x;
    int c64 = tid & 63, rg = tid >> 6;
    int col = ct * 64 + c64;
    float m = -INFINITY, s = 0.f;
    size_t base = ((size_t)b * 4096 + rc * 256 + rg * 64) * QKVD + 512 + col;
#pragma unroll 8
    for (int r = 0; r < 64; ++r) {
        float v = bf2f(qkv[base + (size_t)r * QKVD]);
        if (v > m) { s *= expf(m - v); m = v; }
        s += expf(v - m);
    }
    ms[rg][c64] = m; ss_[rg][c64] = s;
    __syncthreads();
    if (rg == 0) {
        for (int g = 1; g < 4; ++g) {
            float m2 = ms[g][c64], s2 = ss_[g][c64];
            float mm = fmaxf(m, m2);
            s = s * expf(m - mm) + s2 * expf(m2 - mm);
            m = mm;
        }
        int o = ((b * 8 + ct) * 16 + rc) * 64 + c64;
        pmax[o] = m; psum[o] = s;
    }
}

// stage 2: combine 16 row-chunk partials per column
__global__ void k_kstat2(const float* __restrict__ pmax, const float* __restrict__ psum,
                         float* __restrict__ kmax, float* __restrict__ ksum)
{
    int g = blockIdx.x * 64 + threadIdx.x;      // 0..4095 = [b][c]
    int b = g >> 9, c = g & 511;
    int ct = c >> 6, c64 = c & 63;
    int base = ((b * 8 + ct) * 16) * 64 + c64;
    float m = -INFINITY, s = 0.f;
    for (int rc = 0; rc < 16; ++rc) {
        float m2 = pmax[base + rc * 64], s2 = psum[base + rc * 64];
        float mm = fmaxf(m, m2);
        s = s * expf(m - mm) + s2 * expf(m2 - mm);
        m = mm;
    }
    kmax[g] = m; ksum[g] = s;
}

__global__ void k_zero(float* __restrict__ p)
{
    int i = blockIdx.x * 256 + threadIdx.x;
    ((float4*)p)[i] = make_float4(0.f, 0.f, 0.f, 0.f);
}

// ---------------- context[b,h,d,e] = sum_n softmax_k[n,d] * v[n,e]
__global__ void k_ctx(const u16* __restrict__ qkv, const float* __restrict__ kmax,
                      const float* __restrict__ ksum, float* __restrict__ ctx)
{
    __shared__ float ksh[16 * 65];
    __shared__ float vsh[16 * 65];
    int rc = blockIdx.x, h = blockIdx.y, b = blockIdx.z;
    int tid = threadIdx.x;
    int n = tid >> 4, p = tid & 15;
    int cbase = h * 64 + p * 4;
    float km[4], kiv[4];
#pragma unroll
    for (int j = 0; j < 4; ++j) {
        km[j]  = kmax[b * 512 + cbase + j];
        kiv[j] = 1.f / ksum[b * 512 + cbase + j];
    }
    int d0 = (tid & 15) * 4, e0 = (tid >> 4) * 4;
    float acc[4][4] = {};
    for (int it = 0; it < 16; ++it) {
        size_t row = (size_t)b * 4096 + rc * 256 + it * 16 + n;
        ushort4 ku = *(const ushort4*)&qkv[row * QKVD + 512  + cbase];
        ushort4 vu = *(const ushort4*)&qkv[row * QKVD + 1024 + cbase];
        __syncthreads();
        ksh[n*65 + p*4 + 0] = expf(bf2f(ku.x) - km[0]) * kiv[0];
        ksh[n*65 + p*4 + 1] = expf(bf2f(ku.y) - km[1]) * kiv[1];
        ksh[n*65 + p*4 + 2] = expf(bf2f(ku.z) - km[2]) * kiv[2];
        ksh[n*65 + p*4 + 3] = expf(bf2f(ku.w) - km[3]) * kiv[3];
        vsh[n*65 + p*4 + 0] = bf2f(vu.x);
        vsh[n*65 + p*4 + 1] = bf2f(vu.y);
        vsh[n*65 + p*4 + 2] = bf2f(vu.z);
        vsh[n*65 + p*4 + 3] = bf2f(vu.w);
        __syncthreads();
#pragma unroll
        for (int nn = 0; nn < 16; ++nn) {
            float kv[4], vv[4];
#pragma unroll
            for (int i = 0; i < 4; ++i) kv[i] = ksh[nn*65 + d0 + i];
#pragma unroll
            for (int j = 0; j < 4; ++j) vv[j] = vsh[nn*65 + e0 + j];
#pragma unroll
            for (int i = 0; i < 4; ++i)
#pragma unroll
                for (int j = 0; j < 4; ++j) acc[i][j] += kv[i] * vv[j];
        }
    }
    float* cp = ctx + (size_t)(b * 8 + h) * 64 * 64;
#pragma unroll
    for (int i = 0; i < 4; ++i)
#pragma unroll
        for (int j = 0; j < 4; ++j)
            atomicAdd(&cp[(d0 + i) * 64 + e0 + j], acc[i][j]);
}

// ---------------- Wc[b][j][h*64+d] = sum_e ctx[b,h,d,e] * w_out[j][h*64+e]  (bf16 out)
__global__ void k_wc(const float* __restrict__ ctx, const float* __restrict__ w_out, u16* __restrict__ Wc)
{
    __shared__ float csh[64 * 65];
    __shared__ float wsh[64 * 65];
    int jt = blockIdx.x, h = blockIdx.y, b = blockIdx.z;
    int tid = threadIdx.x;
    const float* cp = ctx + (size_t)(b * 8 + h) * 64 * 64;
    for (int idx = tid; idx < 4096; idx += 256) {
        int d = idx >> 6, e = idx & 63;
        csh[d * 65 + e] = cp[idx];
        wsh[d * 65 + e] = w_out[(size_t)(jt * 64 + d) * 512 + h * 64 + e];
    }
    __syncthreads();
    int j0 = (tid >> 4) * 4, d0 = (tid & 15) * 4;
    float acc[4][4] = {};
    for (int e = 0; e < 64; ++e) {
        float wv[4], cv[4];
#pragma unroll
        for (int i = 0; i < 4; ++i) wv[i] = wsh[(j0 + i) * 65 + e];
#pragma unroll
        for (int j = 0; j < 4; ++j) cv[j] = csh[(d0 + j) * 65 + e];
#pragma unroll
        for (int i = 0; i < 4; ++i)
#pragma unroll
            for (int j = 0; j < 4; ++j) acc[i][j] += wv[i] * cv[j];
    }
#pragma unroll
    for (int i = 0; i < 4; ++i)
#pragma unroll
        for (int j = 0; j < 4; ++j)
            Wc[((size_t)b * 512 + jt * 64 + j0 + i) * 512 + h * 64 + d0 + j] = f2bf(acc[i][j]);
}

// ---------------- q softmax over feature dim (64 per head), * 1/8, in place
__global__ void k_qsm(u16* __restrict__ qkv)
{
    int tid = threadIdx.x;
    int g = blockIdx.x * 16 + (tid >> 4);   // head-row id
    int lg = tid & 15;
    int t = g >> 3, h = g & 7;
    size_t base = (size_t)t * QKVD + h * 64 + lg * 4;
    ushort4 u = *(const ushort4*)&qkv[base];
    float v[4] = { bf2f(u.x), bf2f(u.y), bf2f(u.z), bf2f(u.w) };
    float mx = fmaxf(fmaxf(v[0], v[1]), fmaxf(v[2], v[3]));
#pragma unroll
    for (int m = 1; m < 16; m <<= 1) mx = fmaxf(mx, __shfl_xor(mx, m, 16));
    float e[4], s = 0.f;
#pragma unroll
    for (int j = 0; j < 4; ++j) { e[j] = expf(v[j] - mx); s += e[j]; }
#pragma unroll
    for (int m = 1; m < 16; m <<= 1) s += __shfl_xor(s, m, 16);
    float r = 0.125f / s;
    ushort4 o; o.x = f2bf(e[0]*r); o.y = f2bf(e[1]*r); o.z = f2bf(e[2]*r); o.w = f2bf(e[3]*r);
    *(ushort4*)&qkv[base] = o;
}

// ---------------- final LayerNorm: out = LN(pre) * gamma_out ; one wave per token
__global__ void k_lnout(const float* __restrict__ pre, const float* __restrict__ gamma,
                        float* __restrict__ out)
{
    int wave = threadIdx.x >> 6, lane = threadIdx.x & 63;
    size_t t = (size_t)blockIdx.x * 4 + wave;
    const float* xr = pre + t * 512;
    float4 v0 = ((const float4*)xr)[lane * 2];
    float4 v1 = ((const float4*)xr)[lane * 2 + 1];
    float s  = v0.x+v0.y+v0.z+v0.w + v1.x+v1.y+v1.z+v1.w;
    float ss = v0.x*v0.x+v0.y*v0.y+v0.z*v0.z+v0.w*v0.w
             + v1.x*v1.x+v1.y*v1.y+v1.z*v1.z+v1.w*v1.w;
#pragma unroll
    for (int m = 1; m < 64; m <<= 1) { s += __shfl_xor(s, m, 64); ss += __shfl_xor(ss, m, 64); }
    float mu = s * (1.f/512.f);
    float var = ss * (1.f/512.f) - mu * mu;
    float rs = rsqrtf(var + 1e-5f);
    float4 g0 = ((const float4*)gamma)[lane*2], g1 = ((const float4*)gamma)[lane*2+1];
    float4 o0, o1;
    o0.x = (v0.x-mu)*rs*g0.x; o0.y = (v0.y-mu)*rs*g0.y;
    o0.z = (v0.z-mu)*rs*g0.z; o0.w = (v0.w-mu)*rs*g0.w;
    o1.x = (v1.x-mu)*rs*g1.x; o1.y = (v1.y-mu)*rs*g1.y;
    o1.z = (v1.z-mu)*rs*g1.z; o1.w = (v1.w-mu)*rs*g1.w;
    float4* orow = (float4*)(out + t * 512);
    orow[lane * 2] = o0; orow[lane * 2 + 1] = o1;
}

extern "C" void kernel_launch(void* const* d_in, const int* in_sizes, int n_in,
                              void* d_out, int out_size, void* d_ws, size_t ws_size,
                              hipStream_t stream)
{
    const float* x        = (const float*)d_in[0];
    const float* ce       = (const float*)d_in[1];
    const float* gamma_in = (const float*)d_in[2];
    const float* w_cond   = (const float*)d_in[3];
    const float* b_cond   = (const float*)d_in[4];
    const float* w_qkv    = (const float*)d_in[5];
    const float* w_out    = (const float*)d_in[6];
    const float* gamma_out= (const float*)d_in[7];
    float* out = (float*)d_out;

    char* ws = (char*)d_ws;
    size_t o = 0;
    auto take = [&](size_t bytes) -> char* {
        char* p = ws + o; o += (bytes + 255) & ~(size_t)255; return p;
    };
    float* cond  = (float*)take(8 * 1024 * 4);
    u16*   wqkvb = (u16*)  take((size_t)1536 * 512 * 2);
    float* kmax  = (float*)take(4096 * 4);
    float* ksum  = (float*)take(4096 * 4);
    float* pmax  = (float*)take(65536 * 4);
    float* psum  = (float*)take(65536 * 4);
    float* ctx   = (float*)take((size_t)8 * 8 * 64 * 64 * 4);
    u16*   Wc    = (u16*)  take((size_t)8 * 512 * 512 * 2);
    u16*   xm    = (u16*)  take((size_t)TOK * 512 * 2);
    u16*   qkv   = (u16*)  take((size_t)TOK * QKVD * 2);
    float* pre   = (float*)take((size_t)TOK * 512 * 4);

    k_cond <<<8, 256, 0, stream>>>(ce, w_cond, b_cond, cond);
    k_w2bf <<<768, 256, 0, stream>>>(w_qkv, wqkvb);
    k_lnmod<<<8192, 256, 0, stream>>>(x, cond, gamma_in, xm);
    k_gemm<1><<<3072, 256, 0, stream>>>(xm, 512, wqkvb, 0, qkv, QKVD, 12);
    k_kstat1<<<dim3(16, 8, 8), 256, 0, stream>>>(qkv, pmax, psum);
    k_kstat2<<<64, 64, 0, stream>>>(pmax, psum, kmax, ksum);
    k_zero <<<256, 256, 0, stream>>>(ctx);
    k_ctx  <<<dim3(16, 8, 8), 256, 0, stream>>>(qkv, kmax, ksum, ctx);
    k_wc   <<<dim3(8, 8, 8), 256, 0, stream>>>(ctx, w_out, Wc);
    k_qsm  <<<16384, 256, 0, stream>>>(qkv);
    k_gemm<0><<<1024, 256, 0, stream>>>(qkv, QKVD, Wc, 512 * 512, pre, 512, 4);
    k_lnout<<<8192, 256, 0, stream>>>(pre, gamma_out, out);
}

// Round 2
// 363.860 us; speedup vs baseline: 1.0060x; 1.0060x over previous
//
#include <hip/hip_runtime.h>
#include <hip/hip_bf16.h>
#include <math.h>

typedef unsigned short u16;
typedef __attribute__((ext_vector_type(4))) float f32x4;
typedef __attribute__((ext_vector_type(8))) short s16x8;

#define B_    8
#define N_    4096
#define DIM_  512
#define TOK   32768     // B_*N_
#define QKVD  1536

__device__ __forceinline__ float bf2f(u16 u) {
    union { unsigned int i; float f; } x; x.i = ((unsigned int)u) << 16; return x.f;
}
__device__ __forceinline__ u16 f2bf(float f) {
    union { float f; unsigned int i; } x; x.f = f;
    unsigned int r = (x.i + 0x7fffu + ((x.i >> 16) & 1u)) >> 16;
    return (u16)r;
}

__device__ __forceinline__ void gload_lds16(const void* g, void* l) {
    __builtin_amdgcn_global_load_lds(
        (const __attribute__((address_space(1))) unsigned int*)g,
        (__attribute__((address_space(3))) unsigned int*)l, 16, 0, 0);
}

// ---------------- conditioning affine: cond[b][j] = silu(ce[b]) . w_cond[j] + b_cond[j]
__global__ void k_cond(const float* __restrict__ ce, const float* __restrict__ w_cond,
                       const float* __restrict__ b_cond, float* __restrict__ cond)
{
    __shared__ float s[512];
    int b = blockIdx.x, tid = threadIdx.x;
    for (int i = tid; i < 512; i += 256) {
        float v = ce[b * 512 + i];
        s[i] = v / (1.f + expf(-v));
    }
    __syncthreads();
    const float4* w4 = (const float4*)w_cond;
    for (int j = tid; j < 1024; j += 256) {
        float acc = b_cond[j];
#pragma unroll 4
        for (int i4 = 0; i4 < 128; ++i4) {
            float4 w = w4[j * 128 + i4];
            acc += s[i4*4+0]*w.x + s[i4*4+1]*w.y + s[i4*4+2]*w.z + s[i4*4+3]*w.w;
        }
        cond[b * 1024 + j] = acc;
    }
}

// ---------------- w_qkv fp32 -> bf16
__global__ void k_w2bf(const float* __restrict__ w, u16* __restrict__ wb)
{
    int i = (blockIdx.x * 256 + threadIdx.x) * 4;
    float4 v = *(const float4*)&w[i];
    ushort4 o; o.x = f2bf(v.x); o.y = f2bf(v.y); o.z = f2bf(v.z); o.w = f2bf(v.w);
    *(ushort4*)&wb[i] = o;
}

// ---------------- pre-LN + modulation -> xm bf16 ; one wave per token
__global__ void k_lnmod(const float* __restrict__ x, const float* __restrict__ cond,
                        const float* __restrict__ gamma, u16* __restrict__ xm)
{
    int wave = threadIdx.x >> 6, lane = threadIdx.x & 63;
    size_t t = (size_t)blockIdx.x * 4 + wave;
    const float* xr = x + t * 512;
    float4 v0 = ((const float4*)xr)[lane * 2];
    float4 v1 = ((const float4*)xr)[lane * 2 + 1];
    float s  = v0.x+v0.y+v0.z+v0.w + v1.x+v1.y+v1.z+v1.w;
    float ss = v0.x*v0.x+v0.y*v0.y+v0.z*v0.z+v0.w*v0.w
             + v1.x*v1.x+v1.y*v1.y+v1.z*v1.z+v1.w*v1.w;
#pragma unroll
    for (int m = 1; m < 64; m <<= 1) { s += __shfl_xor(s, m, 64); ss += __shfl_xor(ss, m, 64); }
    float mu = s * (1.f/512.f);
    float var = ss * (1.f/512.f) - mu * mu;
    float rs = rsqrtf(var + 1e-5f);
    int b = (int)(t >> 12);
    const float* cb = cond + b * 1024;
    float4 g0  = ((const float4*)gamma)[lane*2],     g1  = ((const float4*)gamma)[lane*2+1];
    float4 sc0 = ((const float4*)cb)[lane*2],        sc1 = ((const float4*)cb)[lane*2+1];
    float4 sh0 = ((const float4*)(cb+512))[lane*2],  sh1 = ((const float4*)(cb+512))[lane*2+1];
    ushort4 o0, o1;
    o0.x = f2bf(((v0.x-mu)*rs*g0.x)*(1.f+sc0.x) + sh0.x);
    o0.y = f2bf(((v0.y-mu)*rs*g0.y)*(1.f+sc0.y) + sh0.y);
    o0.z = f2bf(((v0.z-mu)*rs*g0.z)*(1.f+sc0.z) + sh0.z);
    o0.w = f2bf(((v0.w-mu)*rs*g0.w)*(1.f+sc0.w) + sh0.w);
    o1.x = f2bf(((v1.x-mu)*rs*g1.x)*(1.f+sc1.x) + sh1.x);
    o1.y = f2bf(((v1.y-mu)*rs*g1.y)*(1.f+sc1.y) + sh1.y);
    o1.z = f2bf(((v1.z-mu)*rs*g1.z)*(1.f+sc1.z) + sh1.z);
    o1.w = f2bf(((v1.w-mu)*rs*g1.w)*(1.f+sc1.w) + sh1.w);
    ushort4* orow = (ushort4*)(xm + t * 512);
    orow[lane * 2] = o0; orow[lane * 2 + 1] = o1;
}

// ---------------- bf16 MFMA GEMM: Out[m][n] = sum_k A[m][k] * Bm[n][k]
template<int OUT_BF16>
__global__ __launch_bounds__(256, 2)
void k_gemm(const u16* __restrict__ A, int lda,
            const u16* __restrict__ Bm, int perBatchB,
            void* __restrict__ Out, int ldo, int ntiles)
{
    __shared__ __align__(16) u16 As[128 * 32];
    __shared__ __align__(16) u16 Bs[128 * 32];
    int bid = blockIdx.x;
    int bn = bid % ntiles, bm = bid / ntiles;
    int m0 = bm * 128, n0 = bn * 128;
    const u16* Bp = Bm + (size_t)(m0 >> 12) * perBatchB;
    int tid = threadIdx.x;
    int wid = tid >> 6, lane = tid & 63;
    int wr = (wid >> 1) * 64, wc = (wid & 1) * 64;
    int fr = lane & 15, fk = (lane >> 4) * 8;

    f32x4 acc[4][4];
#pragma unroll
    for (int m = 0; m < 4; ++m)
#pragma unroll
        for (int n = 0; n < 4; ++n) acc[m][n] = (f32x4)0.f;

    for (int k0 = 0; k0 < 512; k0 += 32) {
#pragma unroll
        for (int i = 0; i < 2; ++i) {
            int chunk = tid + i * 256;
            int row = chunk >> 2, part = chunk & 3;
            gload_lds16(A  + (size_t)(m0 + row) * lda + k0 + part * 8, &As[chunk * 8]);
            gload_lds16(Bp + (size_t)(n0 + row) * 512 + k0 + part * 8, &Bs[chunk * 8]);
        }
        __syncthreads();
        s16x8 af[4], bfr[4];
#pragma unroll
        for (int m = 0; m < 4; ++m) af[m]  = *(const s16x8*)&As[(wr + m*16 + fr) * 32 + fk];
#pragma unroll
        for (int n = 0; n < 4; ++n) bfr[n] = *(const s16x8*)&Bs[(wc + n*16 + fr) * 32 + fk];
#pragma unroll
        for (int m = 0; m < 4; ++m)
#pragma unroll
            for (int n = 0; n < 4; ++n)
                acc[m][n] = __builtin_amdgcn_mfma_f32_16x16x32_bf16(af[m], bfr[n], acc[m][n], 0, 0, 0);
        __syncthreads();
    }

    int rbase = m0 + wr + (lane >> 4) * 4;
    int cbase = n0 + wc + (lane & 15);
#pragma unroll
    for (int m = 0; m < 4; ++m)
#pragma unroll
        for (int n = 0; n < 4; ++n)
#pragma unroll
            for (int r = 0; r < 4; ++r) {
                size_t idx = (size_t)(rbase + m*16 + r) * ldo + (cbase + n*16);
                float v = acc[m][n][r];
                if (OUT_BF16) ((u16*)Out)[idx] = f2bf(v);
                else          ((float*)Out)[idx] = v;
            }
}

// ---------------- k column stats: two-pass (max, then sum-exp), coalesced
// block = (rc, b): rows rc*256..+256, all 512 k-cols; thread owns 2 cols.
__global__ void k_kstat1(const u16* __restrict__ qkv, float* __restrict__ pmax, float* __restrict__ psum)
{
    int rc = blockIdx.x, b = blockIdx.y, tid = threadIdx.x;
    const u16* p = qkv + ((size_t)b * 4096 + rc * 256) * QKVD + 512 + tid * 2;
    float m0 = -1e30f, m1 = -1e30f;
#pragma unroll 8
    for (int r = 0; r < 256; ++r) {
        unsigned int u = *(const unsigned int*)&p[(size_t)r * QKVD];
        m0 = fmaxf(m0, bf2f((u16)u));
        m1 = fmaxf(m1, bf2f((u16)(u >> 16)));
    }
    float s0 = 0.f, s1 = 0.f;
#pragma unroll 8
    for (int r = 0; r < 256; ++r) {
        unsigned int u = *(const unsigned int*)&p[(size_t)r * QKVD];
        s0 += __expf(bf2f((u16)u) - m0);
        s1 += __expf(bf2f((u16)(u >> 16)) - m1);
    }
    int o = (b * 16 + rc) * 512 + tid * 2;
    pmax[o] = m0; pmax[o + 1] = m1;
    psum[o] = s0; psum[o + 1] = s1;
}

// stage 2: combine 16 row-chunk partials per column
__global__ void k_kstat2(const float* __restrict__ pmax, const float* __restrict__ psum,
                         float* __restrict__ kmax, float* __restrict__ ksum)
{
    int g = blockIdx.x * 64 + threadIdx.x;      // b*512 + c
    int b = g >> 9, c = g & 511;
    float m = -1e30f, s = 0.f;
    for (int rc = 0; rc < 16; ++rc) {
        float m2 = pmax[(b * 16 + rc) * 512 + c], s2 = psum[(b * 16 + rc) * 512 + c];
        float mm = fmaxf(m, m2);
        s = s * __expf(m - mm) + s2 * __expf(m2 - mm);
        m = mm;
    }
    kmax[g] = m; ksum[g] = s;
}

__global__ void k_zero(float* __restrict__ p)
{
    int i = blockIdx.x * 256 + threadIdx.x;
    ((float4*)p)[i] = make_float4(0.f, 0.f, 0.f, 0.f);
}

// ---------------- context (MFMA): ctx[b,h,d,e] += sum_n exp(k[n,d]-km[d]) * v[n,e]
// normalization 1/ksum[d] applied later in k_wc (it is per-d linear).
// grid (nc=8, h=8, b=8), 256 thr; each wave owns private LDS tiles [64][40] u16,
// processes 32 rows per iter, 4 iters (block covers 512 rows). No __syncthreads.
__global__ __launch_bounds__(256, 2)
void k_ctx(const u16* __restrict__ qkv, const float* __restrict__ kmax, float* __restrict__ ctx)
{
    __shared__ __align__(16) u16 sA[4][64 * 40];
    __shared__ __align__(16) u16 sB[4][64 * 40];
    int nc = blockIdx.x, h = blockIdx.y, b = blockIdx.z;
    int wid = threadIdx.x >> 6, lane = threadIdx.x & 63;
    u16* A  = sA[wid];
    u16* Bt = sB[wid];
    float km = kmax[b * 512 + h * 64 + lane];
    int fr = lane & 15, fk = (lane >> 4) * 8;
    f32x4 acc[4][4];
#pragma unroll
    for (int m = 0; m < 4; ++m)
#pragma unroll
        for (int n = 0; n < 4; ++n) acc[m][n] = (f32x4)0.f;

    size_t rowbase = (size_t)b * 4096 + nc * 512 + wid * 32;
    const u16* kp = qkv + rowbase * QKVD + 512 + h * 64 + lane;
    const u16* vp = kp + 512;

    for (int it = 0; it < 4; ++it) {
        const u16* kq = kp + (size_t)it * 128 * QKVD;
        const u16* vq = vp + (size_t)it * 128 * QKVD;
        unsigned int pk[16], pv[16];
#pragma unroll
        for (int j = 0; j < 16; ++j) {
            float a0 = __expf(bf2f(kq[(size_t)(2*j)   * QKVD]) - km);
            float a1 = __expf(bf2f(kq[(size_t)(2*j+1) * QKVD]) - km);
            pk[j] = (unsigned)f2bf(a0) | ((unsigned)f2bf(a1) << 16);
            float b0 = bf2f(vq[(size_t)(2*j)   * QKVD]);
            float b1 = bf2f(vq[(size_t)(2*j+1) * QKVD]);
            pv[j] = (unsigned)f2bf(b0) | ((unsigned)f2bf(b1) << 16);
        }
        // LDS [feat=lane][n 0..31], row stride 40 u16 (80B: 16B-aligned, spread banks)
#pragma unroll
        for (int j = 0; j < 4; ++j) {
            *(uint4*)&A [lane * 40 + j * 8] = *(uint4*)&pk[j * 4];
            *(uint4*)&Bt[lane * 40 + j * 8] = *(uint4*)&pv[j * 4];
        }
        s16x8 af[4], bfr[4];
#pragma unroll
        for (int m = 0; m < 4; ++m) af[m]  = *(const s16x8*)&A [(m * 16 + fr) * 40 + fk];
#pragma unroll
        for (int n = 0; n < 4; ++n) bfr[n] = *(const s16x8*)&Bt[(n * 16 + fr) * 40 + fk];
#pragma unroll
        for (int m = 0; m < 4; ++m)
#pragma unroll
            for (int n = 0; n < 4; ++n)
                acc[m][n] = __builtin_amdgcn_mfma_f32_16x16x32_bf16(af[m], bfr[n], acc[m][n], 0, 0, 0);
    }

    float* cp = ctx + (size_t)(b * 8 + h) * 64 * 64;
    int rbase = (lane >> 4) * 4, cbase = lane & 15;
#pragma unroll
    for (int m = 0; m < 4; ++m)
#pragma unroll
        for (int n = 0; n < 4; ++n)
#pragma unroll
            for (int r = 0; r < 4; ++r)
                atomicAdd(&cp[(m * 16 + rbase + r) * 64 + n * 16 + cbase], acc[m][n][r]);
}

// ---------------- Wc[b][j][h*64+d] = sum_e (ctx[b,h,d,e]/ksum[b,h,d]) * w_out[j][h*64+e]
__global__ void k_wc(const float* __restrict__ ctx, const float* __restrict__ ksum,
                     const float* __restrict__ w_out, u16* __restrict__ Wc)
{
    __shared__ float csh[64 * 65];
    __shared__ float wsh[64 * 65];
    int jt = blockIdx.x, h = blockIdx.y, b = blockIdx.z;
    int tid = threadIdx.x;
    const float* cp = ctx + (size_t)(b * 8 + h) * 64 * 64;
    for (int idx = tid; idx < 4096; idx += 256) {
        int d = idx >> 6, e = idx & 63;
        csh[d * 65 + e] = cp[idx] * (1.f / ksum[b * 512 + h * 64 + d]);
        wsh[d * 65 + e] = w_out[(size_t)(jt * 64 + d) * 512 + h * 64 + e];
    }
    __syncthreads();
    int j0 = (tid >> 4) * 4, d0 = (tid & 15) * 4;
    float acc[4][4] = {};
    for (int e = 0; e < 64; ++e) {
        float wv[4], cv[4];
#pragma unroll
        for (int i = 0; i < 4; ++i) wv[i] = wsh[(j0 + i) * 65 + e];
#pragma unroll
        for (int j = 0; j < 4; ++j) cv[j] = csh[(d0 + j) * 65 + e];
#pragma unroll
        for (int i = 0; i < 4; ++i)
#pragma unroll
            for (int j = 0; j < 4; ++j) acc[i][j] += wv[i] * cv[j];
    }
#pragma unroll
    for (int i = 0; i < 4; ++i)
#pragma unroll
        for (int j = 0; j < 4; ++j)
            Wc[((size_t)b * 512 + jt * 64 + j0 + i) * 512 + h * 64 + d0 + j] = f2bf(acc[i][j]);
}

// ---------------- q softmax over feature dim (64 per head), * 1/8, in place
__global__ void k_qsm(u16* __restrict__ qkv)
{
    int tid = threadIdx.x;
    int g = blockIdx.x * 16 + (tid >> 4);   // head-row id
    int lg = tid & 15;
    int t = g >> 3, h = g & 7;
    size_t base = (size_t)t * QKVD + h * 64 + lg * 4;
    ushort4 u = *(const ushort4*)&qkv[base];
    float v[4] = { bf2f(u.x), bf2f(u.y), bf2f(u.z), bf2f(u.w) };
    float mx = fmaxf(fmaxf(v[0], v[1]), fmaxf(v[2], v[3]));
#pragma unroll
    for (int m = 1; m < 16; m <<= 1) mx = fmaxf(mx, __shfl_xor(mx, m, 16));
    float e[4], s = 0.f;
#pragma unroll
    for (int j = 0; j < 4; ++j) { e[j] = __expf(v[j] - mx); s += e[j]; }
#pragma unroll
    for (int m = 1; m < 16; m <<= 1) s += __shfl_xor(s, m, 16);
    float r = 0.125f / s;
    ushort4 o; o.x = f2bf(e[0]*r); o.y = f2bf(e[1]*r); o.z = f2bf(e[2]*r); o.w = f2bf(e[3]*r);
    *(ushort4*)&qkv[base] = o;
}

// ---------------- final LayerNorm over bf16 pre: out = LN(pre) * gamma_out
__global__ void k_lnout(const u16* __restrict__ pre, const float* __restrict__ gamma,
                        float* __restrict__ out)
{
    int wave = threadIdx.x >> 6, lane = threadIdx.x & 63;
    size_t t = (size_t)blockIdx.x * 4 + wave;
    const u16* xr = pre + t * 512;
    ushort4 u0 = ((const ushort4*)xr)[lane * 2];
    ushort4 u1 = ((const ushort4*)xr)[lane * 2 + 1];
    float v[8] = { bf2f(u0.x), bf2f(u0.y), bf2f(u0.z), bf2f(u0.w),
                   bf2f(u1.x), bf2f(u1.y), bf2f(u1.z), bf2f(u1.w) };
    float s = 0.f, ss = 0.f;
#pragma unroll
    for (int j = 0; j < 8; ++j) { s += v[j]; ss += v[j] * v[j]; }
#pragma unroll
    for (int m = 1; m < 64; m <<= 1) { s += __shfl_xor(s, m, 64); ss += __shfl_xor(ss, m, 64); }
    float mu = s * (1.f/512.f);
    float var = ss * (1.f/512.f) - mu * mu;
    float rs = rsqrtf(var + 1e-5f);
    float4 g0 = ((const float4*)gamma)[lane*2], g1 = ((const float4*)gamma)[lane*2+1];
    float g[8] = { g0.x, g0.y, g0.z, g0.w, g1.x, g1.y, g1.z, g1.w };
    float4 o0, o1;
    o0.x = (v[0]-mu)*rs*g[0]; o0.y = (v[1]-mu)*rs*g[1];
    o0.z = (v[2]-mu)*rs*g[2]; o0.w = (v[3]-mu)*rs*g[3];
    o1.x = (v[4]-mu)*rs*g[4]; o1.y = (v[5]-mu)*rs*g[5];
    o1.z = (v[6]-mu)*rs*g[6]; o1.w = (v[7]-mu)*rs*g[7];
    float4* orow = (float4*)(out + t * 512);
    orow[lane * 2] = o0; orow[lane * 2 + 1] = o1;
}

extern "C" void kernel_launch(void* const* d_in, const int* in_sizes, int n_in,
                              void* d_out, int out_size, void* d_ws, size_t ws_size,
                              hipStream_t stream)
{
    const float* x        = (const float*)d_in[0];
    const float* ce       = (const float*)d_in[1];
    const float* gamma_in = (const float*)d_in[2];
    const float* w_cond   = (const float*)d_in[3];
    const float* b_cond   = (const float*)d_in[4];
    const float* w_qkv    = (const float*)d_in[5];
    const float* w_out    = (const float*)d_in[6];
    const float* gamma_out= (const float*)d_in[7];
    float* out = (float*)d_out;

    char* ws = (char*)d_ws;
    size_t o = 0;
    auto take = [&](size_t bytes) -> char* {
        char* p = ws + o; o += (bytes + 255) & ~(size_t)255; return p;
    };
    float* cond  = (float*)take(8 * 1024 * 4);
    u16*   wqkvb = (u16*)  take((size_t)1536 * 512 * 2);
    float* kmax  = (float*)take(4096 * 4);
    float* ksum  = (float*)take(4096 * 4);
    float* pmax  = (float*)take(65536 * 4);
    float* psum  = (float*)take(65536 * 4);
    float* ctx   = (float*)take((size_t)8 * 8 * 64 * 64 * 4);
    u16*   Wc    = (u16*)  take((size_t)8 * 512 * 512 * 2);
    u16*   xm    = (u16*)  take((size_t)TOK * 512 * 2);
    u16*   qkv   = (u16*)  take((size_t)TOK * QKVD * 2);
    u16*   preb  = (u16*)  take((size_t)TOK * 512 * 2);

    k_cond <<<8, 256, 0, stream>>>(ce, w_cond, b_cond, cond);
    k_w2bf <<<768, 256, 0, stream>>>(w_qkv, wqkvb);
    k_lnmod<<<8192, 256, 0, stream>>>(x, cond, gamma_in, xm);
    k_gemm<1><<<3072, 256, 0, stream>>>(xm, 512, wqkvb, 0, qkv, QKVD, 12);
    k_kstat1<<<dim3(16, 8), 256, 0, stream>>>(qkv, pmax, psum);
    k_kstat2<<<64, 64, 0, stream>>>(pmax, psum, kmax, ksum);
    k_zero <<<256, 256, 0, stream>>>(ctx);
    k_ctx  <<<dim3(8, 8, 8), 256, 0, stream>>>(qkv, kmax, ctx);
    k_wc   <<<dim3(8, 8, 8), 256, 0, stream>>>(ctx, ksum, w_out, Wc);
    k_qsm  <<<16384, 256, 0, stream>>>(qkv);
    k_gemm<1><<<1024, 256, 0, stream>>>(qkv, QKVD, Wc, 512 * 512, preb, 512, 4);
    k_lnout<<<8192, 256, 0, stream>>>(preb, gamma_out, out);
}

// Round 3
// 263.512 us; speedup vs baseline: 1.3892x; 1.3808x over previous
//
#include <hip/hip_runtime.h>
#include <hip/hip_bf16.h>
#include <math.h>

typedef unsigned short u16;
typedef __attribute__((ext_vector_type(4))) float f32x4;
typedef __attribute__((ext_vector_type(8))) short s16x8;

#define B_    8
#define N_    4096
#define DIM_  512
#define TOK   32768     // B_*N_
#define QKVD  1536

__device__ __forceinline__ float bf2f(u16 u) {
    union { unsigned int i; float f; } x; x.i = ((unsigned int)u) << 16; return x.f;
}
__device__ __forceinline__ u16 f2bf(float f) {
    union { float f; unsigned int i; } x; x.f = f;
    unsigned int r = (x.i + 0x7fffu + ((x.i >> 16) & 1u)) >> 16;
    return (u16)r;
}

__device__ __forceinline__ void gload_lds16(const void* g, void* l) {
    __builtin_amdgcn_global_load_lds(
        (const __attribute__((address_space(1))) unsigned int*)g,
        (__attribute__((address_space(3))) unsigned int*)l, 16, 0, 0);
}

// ---------------- conditioning affine: cond[b][j] = silu(ce[b]) . w_cond[j] + b_cond[j]
// grid (64, 8): 16 j per block, wave-per-j (4 j per wave), lane-contiguous loads.
__global__ void k_cond(const float* __restrict__ ce, const float* __restrict__ w_cond,
                       const float* __restrict__ b_cond, float* __restrict__ cond)
{
    __shared__ float s[512];
    int jt = blockIdx.x, b = blockIdx.y;
    int tid = threadIdx.x, wid = tid >> 6, lane = tid & 63;
    for (int i = tid; i < 512; i += 256) {
        float v = ce[b * 512 + i];
        s[i] = v / (1.f + __expf(-v));
    }
    __syncthreads();
#pragma unroll
    for (int jj = 0; jj < 4; ++jj) {
        int j = jt * 16 + wid * 4 + jj;
        const float4* w4 = (const float4*)(w_cond + (size_t)j * 512);
        float4 a = w4[lane * 2], c = w4[lane * 2 + 1];
        float acc = a.x*s[lane*8+0] + a.y*s[lane*8+1] + a.z*s[lane*8+2] + a.w*s[lane*8+3]
                  + c.x*s[lane*8+4] + c.y*s[lane*8+5] + c.z*s[lane*8+6] + c.w*s[lane*8+7];
#pragma unroll
        for (int d = 1; d < 64; d <<= 1) acc += __shfl_xor(acc, d, 64);
        if (lane == 0) cond[b * 1024 + j] = acc + b_cond[j];
    }
}

// ---------------- w_qkv fp32 -> bf16
__global__ void k_w2bf(const float* __restrict__ w, u16* __restrict__ wb)
{
    int i = (blockIdx.x * 256 + threadIdx.x) * 4;
    float4 v = *(const float4*)&w[i];
    ushort4 o; o.x = f2bf(v.x); o.y = f2bf(v.y); o.z = f2bf(v.z); o.w = f2bf(v.w);
    *(ushort4*)&wb[i] = o;
}

// ---------------- pre-LN + modulation -> xm bf16 ; one wave per token
__global__ void k_lnmod(const float* __restrict__ x, const float* __restrict__ cond,
                        const float* __restrict__ gamma, u16* __restrict__ xm)
{
    int wave = threadIdx.x >> 6, lane = threadIdx.x & 63;
    size_t t = (size_t)blockIdx.x * 4 + wave;
    const float* xr = x + t * 512;
    float4 v0 = ((const float4*)xr)[lane * 2];
    float4 v1 = ((const float4*)xr)[lane * 2 + 1];
    float s  = v0.x+v0.y+v0.z+v0.w + v1.x+v1.y+v1.z+v1.w;
    float ss = v0.x*v0.x+v0.y*v0.y+v0.z*v0.z+v0.w*v0.w
             + v1.x*v1.x+v1.y*v1.y+v1.z*v1.z+v1.w*v1.w;
#pragma unroll
    for (int m = 1; m < 64; m <<= 1) { s += __shfl_xor(s, m, 64); ss += __shfl_xor(ss, m, 64); }
    float mu = s * (1.f/512.f);
    float var = ss * (1.f/512.f) - mu * mu;
    float rs = rsqrtf(var + 1e-5f);
    int b = (int)(t >> 12);
    const float* cb = cond + b * 1024;
    float4 g0  = ((const float4*)gamma)[lane*2],     g1  = ((const float4*)gamma)[lane*2+1];
    float4 sc0 = ((const float4*)cb)[lane*2],        sc1 = ((const float4*)cb)[lane*2+1];
    float4 sh0 = ((const float4*)(cb+512))[lane*2],  sh1 = ((const float4*)(cb+512))[lane*2+1];
    ushort4 o0, o1;
    o0.x = f2bf(((v0.x-mu)*rs*g0.x)*(1.f+sc0.x) + sh0.x);
    o0.y = f2bf(((v0.y-mu)*rs*g0.y)*(1.f+sc0.y) + sh0.y);
    o0.z = f2bf(((v0.z-mu)*rs*g0.z)*(1.f+sc0.z) + sh0.z);
    o0.w = f2bf(((v0.w-mu)*rs*g0.w)*(1.f+sc0.w) + sh0.w);
    o1.x = f2bf(((v1.x-mu)*rs*g1.x)*(1.f+sc1.x) + sh1.x);
    o1.y = f2bf(((v1.y-mu)*rs*g1.y)*(1.f+sc1.y) + sh1.y);
    o1.z = f2bf(((v1.z-mu)*rs*g1.z)*(1.f+sc1.z) + sh1.z);
    o1.w = f2bf(((v1.w-mu)*rs*g1.w)*(1.f+sc1.w) + sh1.w);
    ushort4* orow = (ushort4*)(xm + t * 512);
    orow[lane * 2] = o0; orow[lane * 2 + 1] = o1;
}

// ---------------- bf16 MFMA GEMM: Out[m][n] = sum_k A[m][k] * Bm[n][k]
// MODE 0: plain bf16 store.
// MODE 1 (qkv): bn<4 -> q feature-softmax (*1/8) fused; bn in [4,8) -> k store +
//   per-wave column max/sumexp partials (64-row chunks); bn>=8 -> plain store.
template<int MODE>
__global__ __launch_bounds__(256, 2)
void k_gemm(const u16* __restrict__ A, int lda,
            const u16* __restrict__ Bm, int perBatchB,
            u16* __restrict__ Out, int ldo, int ntiles,
            float* __restrict__ pmax, float* __restrict__ psum)
{
    __shared__ __align__(16) u16 As[128 * 32];
    __shared__ __align__(16) u16 Bs[128 * 32];
    int bid = blockIdx.x;
    int bn = bid % ntiles, bm = bid / ntiles;
    int m0 = bm * 128, n0 = bn * 128;
    const u16* Bp = Bm + (size_t)(m0 >> 12) * perBatchB;
    int tid = threadIdx.x;
    int wid = tid >> 6, lane = tid & 63;
    int wr = (wid >> 1) * 64, wc = (wid & 1) * 64;
    int fr = lane & 15, fk = (lane >> 4) * 8;

    f32x4 acc[4][4];
#pragma unroll
    for (int m = 0; m < 4; ++m)
#pragma unroll
        for (int n = 0; n < 4; ++n) acc[m][n] = (f32x4)0.f;

    for (int k0 = 0; k0 < 512; k0 += 32) {
#pragma unroll
        for (int i = 0; i < 2; ++i) {
            int chunk = tid + i * 256;
            int row = chunk >> 2, part = chunk & 3;
            gload_lds16(A  + (size_t)(m0 + row) * lda + k0 + part * 8, &As[chunk * 8]);
            gload_lds16(Bp + (size_t)(n0 + row) * 512 + k0 + part * 8, &Bs[chunk * 8]);
        }
        __syncthreads();
        s16x8 af[4], bfr[4];
#pragma unroll
        for (int m = 0; m < 4; ++m) af[m]  = *(const s16x8*)&As[(wr + m*16 + fr) * 32 + fk];
#pragma unroll
        for (int n = 0; n < 4; ++n) bfr[n] = *(const s16x8*)&Bs[(wc + n*16 + fr) * 32 + fk];
#pragma unroll
        for (int m = 0; m < 4; ++m)
#pragma unroll
            for (int n = 0; n < 4; ++n)
                acc[m][n] = __builtin_amdgcn_mfma_f32_16x16x32_bf16(af[m], bfr[n], acc[m][n], 0, 0, 0);
        __syncthreads();
    }

    int rbase = m0 + wr + (lane >> 4) * 4;
    int cbase = n0 + wc + (lane & 15);

    if (MODE == 1 && bn < 4) {
        // q: softmax over the wave's 64 cols (= one head), scale 1/8
#pragma unroll
        for (int m = 0; m < 4; ++m) {
            float v[4][4];
#pragma unroll
            for (int n = 0; n < 4; ++n)
#pragma unroll
                for (int r = 0; r < 4; ++r) v[n][r] = acc[m][n][r];
#pragma unroll
            for (int r = 0; r < 4; ++r) {
                float mx = fmaxf(fmaxf(v[0][r], v[1][r]), fmaxf(v[2][r], v[3][r]));
#pragma unroll
                for (int d = 1; d < 16; d <<= 1) mx = fmaxf(mx, __shfl_xor(mx, d, 64));
                float e0 = __expf(v[0][r]-mx), e1 = __expf(v[1][r]-mx);
                float e2 = __expf(v[2][r]-mx), e3 = __expf(v[3][r]-mx);
                float sm = e0 + e1 + e2 + e3;
#pragma unroll
                for (int d = 1; d < 16; d <<= 1) sm += __shfl_xor(sm, d, 64);
                float rv = 0.125f / sm;
                v[0][r] = e0*rv; v[1][r] = e1*rv; v[2][r] = e2*rv; v[3][r] = e3*rv;
            }
#pragma unroll
            for (int n = 0; n < 4; ++n)
#pragma unroll
                for (int r = 0; r < 4; ++r)
                    Out[(size_t)(rbase + m*16 + r) * ldo + (cbase + n*16)] = f2bf(v[n][r]);
        }
    } else if (MODE == 1 && bn < 8) {
        // k: store + per-wave per-column partial max/sumexp over 64 rows
        int bloc = m0 >> 12;
        int rcc = ((m0 & 4095) + wr) >> 6;
#pragma unroll
        for (int n = 0; n < 4; ++n) {
            float vv[16]; float mx = -1e30f;
#pragma unroll
            for (int m = 0; m < 4; ++m)
#pragma unroll
                for (int r = 0; r < 4; ++r) {
                    u16 u = f2bf(acc[m][n][r]);
                    Out[(size_t)(rbase + m*16 + r) * ldo + (cbase + n*16)] = u;
                    float vf = bf2f(u);
                    vv[m*4+r] = vf; mx = fmaxf(mx, vf);
                }
            mx = fmaxf(mx, __shfl_xor(mx, 16, 64));
            mx = fmaxf(mx, __shfl_xor(mx, 32, 64));
            float sm = 0.f;
#pragma unroll
            for (int i = 0; i < 16; ++i) sm += __expf(vv[i] - mx);
            sm += __shfl_xor(sm, 16, 64);
            sm += __shfl_xor(sm, 32, 64);
            if (lane < 16) {
                int kcol = (n0 - 512) + wc + n*16 + lane;
                int o = (bloc * 64 + rcc) * 512 + kcol;
                pmax[o] = mx; psum[o] = sm;
            }
        }
    } else {
#pragma unroll
        for (int m = 0; m < 4; ++m)
#pragma unroll
            for (int n = 0; n < 4; ++n)
#pragma unroll
                for (int r = 0; r < 4; ++r)
                    Out[(size_t)(rbase + m*16 + r) * ldo + (cbase + n*16)] = f2bf(acc[m][n][r]);
    }
}

// stage 2: combine 64 row-chunk partials per column
__global__ void k_kstat2(const float* __restrict__ pmax, const float* __restrict__ psum,
                         float* __restrict__ kmax, float* __restrict__ ksum)
{
    int g = blockIdx.x * 64 + threadIdx.x;      // b*512 + c
    int b = g >> 9, c = g & 511;
    float m = -1e30f, s = 0.f;
    for (int rc = 0; rc < 64; ++rc) {
        float m2 = pmax[(b * 64 + rc) * 512 + c], s2 = psum[(b * 64 + rc) * 512 + c];
        float mm = fmaxf(m, m2);
        s = s * __expf(m - mm) + s2 * __expf(m2 - mm);
        m = mm;
    }
    kmax[g] = m; ksum[g] = s;
}

__global__ void k_zero(float* __restrict__ p)
{
    int i = blockIdx.x * 256 + threadIdx.x;
    ((float4*)p)[i] = make_float4(0.f, 0.f, 0.f, 0.f);
}

// ---------------- context (MFMA): ctx[b,h,d,e] += sum_n exp(k[n,d]-km[d]) * v[n,e]
__global__ __launch_bounds__(256, 2)
void k_ctx(const u16* __restrict__ qkv, const float* __restrict__ kmax, float* __restrict__ ctx)
{
    __shared__ __align__(16) u16 sA[4][64 * 40];
    __shared__ __align__(16) u16 sB[4][64 * 40];
    int nc = blockIdx.x, h = blockIdx.y, b = blockIdx.z;
    int wid = threadIdx.x >> 6, lane = threadIdx.x & 63;
    u16* A  = sA[wid];
    u16* Bt = sB[wid];
    float km = kmax[b * 512 + h * 64 + lane];
    int fr = lane & 15, fk = (lane >> 4) * 8;
    f32x4 acc[4][4];
#pragma unroll
    for (int m = 0; m < 4; ++m)
#pragma unroll
        for (int n = 0; n < 4; ++n) acc[m][n] = (f32x4)0.f;

    size_t rowbase = (size_t)b * 4096 + nc * 512 + wid * 32;
    const u16* kp = qkv + rowbase * QKVD + 512 + h * 64 + lane;
    const u16* vp = kp + 512;

    for (int it = 0; it < 4; ++it) {
        const u16* kq = kp + (size_t)it * 128 * QKVD;
        const u16* vq = vp + (size_t)it * 128 * QKVD;
        unsigned int pk[16], pv[16];
#pragma unroll
        for (int j = 0; j < 16; ++j) {
            float a0 = __expf(bf2f(kq[(size_t)(2*j)   * QKVD]) - km);
            float a1 = __expf(bf2f(kq[(size_t)(2*j+1) * QKVD]) - km);
            pk[j] = (unsigned)f2bf(a0) | ((unsigned)f2bf(a1) << 16);
            float b0 = bf2f(vq[(size_t)(2*j)   * QKVD]);
            float b1 = bf2f(vq[(size_t)(2*j+1) * QKVD]);
            pv[j] = (unsigned)f2bf(b0) | ((unsigned)f2bf(b1) << 16);
        }
#pragma unroll
        for (int j = 0; j < 4; ++j) {
            *(uint4*)&A [lane * 40 + j * 8] = *(uint4*)&pk[j * 4];
            *(uint4*)&Bt[lane * 40 + j * 8] = *(uint4*)&pv[j * 4];
        }
        s16x8 af[4], bfr[4];
#pragma unroll
        for (int m = 0; m < 4; ++m) af[m]  = *(const s16x8*)&A [(m * 16 + fr) * 40 + fk];
#pragma unroll
        for (int n = 0; n < 4; ++n) bfr[n] = *(const s16x8*)&Bt[(n * 16 + fr) * 40 + fk];
#pragma unroll
        for (int m = 0; m < 4; ++m)
#pragma unroll
            for (int n = 0; n < 4; ++n)
                acc[m][n] = __builtin_amdgcn_mfma_f32_16x16x32_bf16(af[m], bfr[n], acc[m][n], 0, 0, 0);
    }

    float* cp = ctx + (size_t)(b * 8 + h) * 64 * 64;
    int rbase = (lane >> 4) * 4, cbase = lane & 15;
#pragma unroll
    for (int m = 0; m < 4; ++m)
#pragma unroll
        for (int n = 0; n < 4; ++n)
#pragma unroll
            for (int r = 0; r < 4; ++r)
                atomicAdd(&cp[(m * 16 + rbase + r) * 64 + n * 16 + cbase], acc[m][n][r]);
}

// ---------------- Wc[b][j][h*64+d] = sum_e (ctx[b,h,d,e]/ksum[b,h,d]) * w_out[j][h*64+e]
__global__ void k_wc(const float* __restrict__ ctx, const float* __restrict__ ksum,
                     const float* __restrict__ w_out, u16* __restrict__ Wc)
{
    __shared__ float csh[64 * 65];
    __shared__ float wsh[64 * 65];
    int jt = blockIdx.x, h = blockIdx.y, b = blockIdx.z;
    int tid = threadIdx.x;
    const float* cp = ctx + (size_t)(b * 8 + h) * 64 * 64;
    for (int idx = tid; idx < 4096; idx += 256) {
        int d = idx >> 6, e = idx & 63;
        csh[d * 65 + e] = cp[idx] * (1.f / ksum[b * 512 + h * 64 + d]);
        wsh[d * 65 + e] = w_out[(size_t)(jt * 64 + d) * 512 + h * 64 + e];
    }
    __syncthreads();
    int j0 = (tid >> 4) * 4, d0 = (tid & 15) * 4;
    float acc[4][4] = {};
    for (int e = 0; e < 64; ++e) {
        float wv[4], cv[4];
#pragma unroll
        for (int i = 0; i < 4; ++i) wv[i] = wsh[(j0 + i) * 65 + e];
#pragma unroll
        for (int j = 0; j < 4; ++j) cv[j] = csh[(d0 + j) * 65 + e];
#pragma unroll
        for (int i = 0; i < 4; ++i)
#pragma unroll
            for (int j = 0; j < 4; ++j) acc[i][j] += wv[i] * cv[j];
    }
#pragma unroll
    for (int i = 0; i < 4; ++i)
#pragma unroll
        for (int j = 0; j < 4; ++j)
            Wc[((size_t)b * 512 + jt * 64 + j0 + i) * 512 + h * 64 + d0 + j] = f2bf(acc[i][j]);
}

// ---------------- final LayerNorm over bf16 pre: out = LN(pre) * gamma_out
__global__ void k_lnout(const u16* __restrict__ pre, const float* __restrict__ gamma,
                        float* __restrict__ out)
{
    int wave = threadIdx.x >> 6, lane = threadIdx.x & 63;
    size_t t = (size_t)blockIdx.x * 4 + wave;
    const u16* xr = pre + t * 512;
    ushort4 u0 = ((const ushort4*)xr)[lane * 2];
    ushort4 u1 = ((const ushort4*)xr)[lane * 2 + 1];
    float v[8] = { bf2f(u0.x), bf2f(u0.y), bf2f(u0.z), bf2f(u0.w),
                   bf2f(u1.x), bf2f(u1.y), bf2f(u1.z), bf2f(u1.w) };
    float s = 0.f, ss = 0.f;
#pragma unroll
    for (int j = 0; j < 8; ++j) { s += v[j]; ss += v[j] * v[j]; }
#pragma unroll
    for (int m = 1; m < 64; m <<= 1) { s += __shfl_xor(s, m, 64); ss += __shfl_xor(ss, m, 64); }
    float mu = s * (1.f/512.f);
    float var = ss * (1.f/512.f) - mu * mu;
    float rs = rsqrtf(var + 1e-5f);
    float4 g0 = ((const float4*)gamma)[lane*2], g1 = ((const float4*)gamma)[lane*2+1];
    float g[8] = { g0.x, g0.y, g0.z, g0.w, g1.x, g1.y, g1.z, g1.w };
    float4 o0, o1;
    o0.x = (v[0]-mu)*rs*g[0]; o0.y = (v[1]-mu)*rs*g[1];
    o0.z = (v[2]-mu)*rs*g[2]; o0.w = (v[3]-mu)*rs*g[3];
    o1.x = (v[4]-mu)*rs*g[4]; o1.y = (v[5]-mu)*rs*g[5];
    o1.z = (v[6]-mu)*rs*g[6]; o1.w = (v[7]-mu)*rs*g[7];
    float4* orow = (float4*)(out + t * 512);
    orow[lane * 2] = o0; orow[lane * 2 + 1] = o1;
}

extern "C" void kernel_launch(void* const* d_in, const int* in_sizes, int n_in,
                              void* d_out, int out_size, void* d_ws, size_t ws_size,
                              hipStream_t stream)
{
    const float* x        = (const float*)d_in[0];
    const float* ce       = (const float*)d_in[1];
    const float* gamma_in = (const float*)d_in[2];
    const float* w_cond   = (const float*)d_in[3];
    const float* b_cond   = (const float*)d_in[4];
    const float* w_qkv    = (const float*)d_in[5];
    const float* w_out    = (const float*)d_in[6];
    const float* gamma_out= (const float*)d_in[7];
    float* out = (float*)d_out;

    char* ws = (char*)d_ws;
    size_t o = 0;
    auto take = [&](size_t bytes) -> char* {
        char* p = ws + o; o += (bytes + 255) & ~(size_t)255; return p;
    };
    float* cond  = (float*)take(8 * 1024 * 4);
    u16*   wqkvb = (u16*)  take((size_t)1536 * 512 * 2);
    float* kmax  = (float*)take(4096 * 4);
    float* ksum  = (float*)take(4096 * 4);
    float* pmax  = (float*)take((size_t)8 * 64 * 512 * 4);
    float* psum  = (float*)take((size_t)8 * 64 * 512 * 4);
    float* ctx   = (float*)take((size_t)8 * 8 * 64 * 64 * 4);
    u16*   Wc    = (u16*)  take((size_t)8 * 512 * 512 * 2);
    u16*   xm    = (u16*)  take((size_t)TOK * 512 * 2);
    u16*   qkv   = (u16*)  take((size_t)TOK * QKVD * 2);
    u16*   preb  = (u16*)  take((size_t)TOK * 512 * 2);

    k_cond <<<dim3(64, 8), 256, 0, stream>>>(ce, w_cond, b_cond, cond);
    k_w2bf <<<768, 256, 0, stream>>>(w_qkv, wqkvb);
    k_lnmod<<<8192, 256, 0, stream>>>(x, cond, gamma_in, xm);
    k_gemm<1><<<3072, 256, 0, stream>>>(xm, 512, wqkvb, 0, qkv, QKVD, 12, pmax, psum);
    k_kstat2<<<64, 64, 0, stream>>>(pmax, psum, kmax, ksum);
    k_zero <<<256, 256, 0, stream>>>(ctx);
    k_ctx  <<<dim3(8, 8, 8), 256, 0, stream>>>(qkv, kmax, ctx);
    k_wc   <<<dim3(8, 8, 8), 256, 0, stream>>>(ctx, ksum, w_out, Wc);
    k_gemm<0><<<1024, 256, 0, stream>>>(qkv, QKVD, Wc, 512 * 512, preb, 512, 4, nullptr, nullptr);
    k_lnout<<<8192, 256, 0, stream>>>(preb, gamma_out, out);
}

// Round 5
// 189.805 us; speedup vs baseline: 1.9286x; 1.3883x over previous
//
#include <hip/hip_runtime.h>
#include <hip/hip_bf16.h>
#include <math.h>

typedef unsigned short u16;
typedef __attribute__((ext_vector_type(4))) float f32x4;
typedef __attribute__((ext_vector_type(8))) short s16x8;

#define B_    8
#define N_    4096
#define DIM_  512
#define TOK   32768     // B_*N_
#define QKVD  1536

__device__ __forceinline__ float bf2f(u16 u) {
    union { unsigned int i; float f; } x; x.i = ((unsigned int)u) << 16; return x.f;
}
__device__ __forceinline__ u16 f2bf(float f) {
    union { float f; unsigned int i; } x; x.f = f;
    unsigned int r = (x.i + 0x7fffu + ((x.i >> 16) & 1u)) >> 16;
    return (u16)r;
}

__device__ __forceinline__ void gload_lds16(const void* g, void* l) {
    __builtin_amdgcn_global_load_lds(
        (const __attribute__((address_space(1))) unsigned int*)g,
        (__attribute__((address_space(3))) unsigned int*)l, 16, 0, 0);
}

// 16B-chunk swizzle: LDS stays linear (gload_lds requirement); global source and
// ds_read both apply the same involution part^(row&7). Rows are 8 chunks (=64 u16).
__device__ __forceinline__ int swz8(int row, int p) { return p ^ (row & 7); }

// ---------------- conditioning affine: cond[b][j] = silu(ce[b]) . w_cond[j] + b_cond[j]
__global__ void k_cond(const float* __restrict__ ce, const float* __restrict__ w_cond,
                       const float* __restrict__ b_cond, float* __restrict__ cond)
{
    __shared__ float s[512];
    int jt = blockIdx.x, b = blockIdx.y;
    int tid = threadIdx.x, wid = tid >> 6, lane = tid & 63;
    for (int i = tid; i < 512; i += 256) {
        float v = ce[b * 512 + i];
        s[i] = v / (1.f + __expf(-v));
    }
    __syncthreads();
#pragma unroll
    for (int jj = 0; jj < 4; ++jj) {
        int j = jt * 16 + wid * 4 + jj;
        const float4* w4 = (const float4*)(w_cond + (size_t)j * 512);
        float4 a = w4[lane * 2], c = w4[lane * 2 + 1];
        float acc = a.x*s[lane*8+0] + a.y*s[lane*8+1] + a.z*s[lane*8+2] + a.w*s[lane*8+3]
                  + c.x*s[lane*8+4] + c.y*s[lane*8+5] + c.z*s[lane*8+6] + c.w*s[lane*8+7];
#pragma unroll
        for (int d = 1; d < 64; d <<= 1) acc += __shfl_xor(acc, d, 64);
        if (lane == 0) cond[b * 1024 + j] = acc + b_cond[j];
    }
}

// ---------------- w_qkv fp32 -> bf16
__global__ void k_w2bf(const float* __restrict__ w, u16* __restrict__ wb)
{
    int i = (blockIdx.x * 256 + threadIdx.x) * 4;
    float4 v = *(const float4*)&w[i];
    ushort4 o; o.x = f2bf(v.x); o.y = f2bf(v.y); o.z = f2bf(v.z); o.w = f2bf(v.w);
    *(ushort4*)&wb[i] = o;
}

// ---------------- pre-LN + modulation -> xm bf16 ; one wave per token
__global__ void k_lnmod(const float* __restrict__ x, const float* __restrict__ cond,
                        const float* __restrict__ gamma, u16* __restrict__ xm)
{
    int wave = threadIdx.x >> 6, lane = threadIdx.x & 63;
    size_t t = (size_t)blockIdx.x * 4 + wave;
    const float* xr = x + t * 512;
    float4 v0 = ((const float4*)xr)[lane * 2];
    float4 v1 = ((const float4*)xr)[lane * 2 + 1];
    float s  = v0.x+v0.y+v0.z+v0.w + v1.x+v1.y+v1.z+v1.w;
    float ss = v0.x*v0.x+v0.y*v0.y+v0.z*v0.z+v0.w*v0.w
             + v1.x*v1.x+v1.y*v1.y+v1.z*v1.z+v1.w*v1.w;
#pragma unroll
    for (int m = 1; m < 64; m <<= 1) { s += __shfl_xor(s, m, 64); ss += __shfl_xor(ss, m, 64); }
    float mu = s * (1.f/512.f);
    float var = ss * (1.f/512.f) - mu * mu;
    float rs = rsqrtf(var + 1e-5f);
    int b = (int)(t >> 12);
    const float* cb = cond + b * 1024;
    float4 g0  = ((const float4*)gamma)[lane*2],     g1  = ((const float4*)gamma)[lane*2+1];
    float4 sc0 = ((const float4*)cb)[lane*2],        sc1 = ((const float4*)cb)[lane*2+1];
    float4 sh0 = ((const float4*)(cb+512))[lane*2],  sh1 = ((const float4*)(cb+512))[lane*2+1];
    ushort4 o0, o1;
    o0.x = f2bf(((v0.x-mu)*rs*g0.x)*(1.f+sc0.x) + sh0.x);
    o0.y = f2bf(((v0.y-mu)*rs*g0.y)*(1.f+sc0.y) + sh0.y);
    o0.z = f2bf(((v0.z-mu)*rs*g0.z)*(1.f+sc0.z) + sh0.z);
    o0.w = f2bf(((v0.w-mu)*rs*g0.w)*(1.f+sc0.w) + sh0.w);
    o1.x = f2bf(((v1.x-mu)*rs*g1.x)*(1.f+sc1.x) + sh1.x);
    o1.y = f2bf(((v1.y-mu)*rs*g1.y)*(1.f+sc1.y) + sh1.y);
    o1.z = f2bf(((v1.z-mu)*rs*g1.z)*(1.f+sc1.z) + sh1.z);
    o1.w = f2bf(((v1.w-mu)*rs*g1.w)*(1.f+sc1.w) + sh1.w);
    ushort4* orow = (ushort4*)(xm + t * 512);
    orow[lane * 2] = o0; orow[lane * 2 + 1] = o1;
}

// ---------------- qkv GEMM (bf16 MFMA, 128x128 tile, BK=64, swizzled LDS)
// fused epilogue: bn<4 -> q feature-softmax (*1/8); bn in [4,8) -> k store +
// per-wave column max/sumexp partials; bn>=8 -> plain store (v).
__global__ __launch_bounds__(256, 2)
void k_gemmqkv(const u16* __restrict__ A,
               const u16* __restrict__ Bm,
               u16* __restrict__ Out,
               float* __restrict__ pmax, float* __restrict__ psum)
{
    __shared__ __align__(16) u16 As[128 * 64];
    __shared__ __align__(16) u16 Bs[128 * 64];
    // XCD-aware swizzle: 3072 blocks, 8 XCDs -> each XCD gets 32 contiguous bm panels
    int sid = (blockIdx.x & 7) * 384 + (blockIdx.x >> 3);
    int bn = sid % 12, bm = sid / 12;
    int m0 = bm * 128, n0 = bn * 128;
    int tid = threadIdx.x;
    int wid = tid >> 6, lane = tid & 63;
    int wr = (wid >> 1) * 64, wc = (wid & 1) * 64;
    int fr = lane & 15, fc = lane >> 4;

    f32x4 acc[4][4];
#pragma unroll
    for (int m = 0; m < 4; ++m)
#pragma unroll
        for (int n = 0; n < 4; ++n) acc[m][n] = (f32x4)0.f;

    for (int k0 = 0; k0 < 512; k0 += 64) {
#pragma unroll
        for (int i = 0; i < 4; ++i) {
            int c = tid + i * 256;
            int row = c >> 3, p = c & 7, gp = swz8(row, p);
            gload_lds16(A  + (size_t)(m0 + row) * 512 + k0 + gp * 8, &As[c * 8]);
            gload_lds16(Bm + (size_t)(n0 + row) * 512 + k0 + gp * 8, &Bs[c * 8]);
        }
        __syncthreads();
#pragma unroll
        for (int kk = 0; kk < 2; ++kk) {
            s16x8 af[4], bfr[4];
            int q = kk * 4 + fc;
#pragma unroll
            for (int m = 0; m < 4; ++m) {
                int row = wr + m * 16 + fr;
                af[m] = *(const s16x8*)&As[(row * 8 + swz8(row, q)) * 8];
            }
#pragma unroll
            for (int n = 0; n < 4; ++n) {
                int row = wc + n * 16 + fr;
                bfr[n] = *(const s16x8*)&Bs[(row * 8 + swz8(row, q)) * 8];
            }
#pragma unroll
            for (int m = 0; m < 4; ++m)
#pragma unroll
                for (int n = 0; n < 4; ++n)
                    acc[m][n] = __builtin_amdgcn_mfma_f32_16x16x32_bf16(af[m], bfr[n], acc[m][n], 0, 0, 0);
        }
        __syncthreads();
    }

    int rbase = m0 + wr + fc * 4;
    int cbase = n0 + wc + fr;

    if (bn < 4) {
        // q: softmax over the wave's 64 cols (= one head), scale 1/8
#pragma unroll
        for (int m = 0; m < 4; ++m) {
            float v[4][4];
#pragma unroll
            for (int n = 0; n < 4; ++n)
#pragma unroll
                for (int r = 0; r < 4; ++r) v[n][r] = acc[m][n][r];
#pragma unroll
            for (int r = 0; r < 4; ++r) {
                float mx = fmaxf(fmaxf(v[0][r], v[1][r]), fmaxf(v[2][r], v[3][r]));
#pragma unroll
                for (int d = 1; d < 16; d <<= 1) mx = fmaxf(mx, __shfl_xor(mx, d, 64));
                float e0 = __expf(v[0][r]-mx), e1 = __expf(v[1][r]-mx);
                float e2 = __expf(v[2][r]-mx), e3 = __expf(v[3][r]-mx);
                float sm = e0 + e1 + e2 + e3;
#pragma unroll
                for (int d = 1; d < 16; d <<= 1) sm += __shfl_xor(sm, d, 64);
                float rv = 0.125f / sm;
                v[0][r] = e0*rv; v[1][r] = e1*rv; v[2][r] = e2*rv; v[3][r] = e3*rv;
            }
#pragma unroll
            for (int n = 0; n < 4; ++n)
#pragma unroll
                for (int r = 0; r < 4; ++r)
                    Out[(size_t)(rbase + m*16 + r) * QKVD + (cbase + n*16)] = f2bf(v[n][r]);
        }
    } else if (bn < 8) {
        // k: store + per-wave per-column partial max/sumexp over 64 rows
        int bloc = m0 >> 12;
        int rcc = ((m0 & 4095) + wr) >> 6;
#pragma unroll
        for (int n = 0; n < 4; ++n) {
            float vv[16]; float mx = -1e30f;
#pragma unroll
            for (int m = 0; m < 4; ++m)
#pragma unroll
                for (int r = 0; r < 4; ++r) {
                    u16 u = f2bf(acc[m][n][r]);
                    Out[(size_t)(rbase + m*16 + r) * QKVD + (cbase + n*16)] = u;
                    float vf = bf2f(u);
                    vv[m*4+r] = vf; mx = fmaxf(mx, vf);
                }
            mx = fmaxf(mx, __shfl_xor(mx, 16, 64));
            mx = fmaxf(mx, __shfl_xor(mx, 32, 64));
            float sm = 0.f;
#pragma unroll
            for (int i = 0; i < 16; ++i) sm += __expf(vv[i] - mx);
            sm += __shfl_xor(sm, 16, 64);
            sm += __shfl_xor(sm, 32, 64);
            if (lane < 16) {
                int kcol = (n0 - 512) + wc + n*16 + lane;
                int o = (bloc * 64 + rcc) * 512 + kcol;
                pmax[o] = mx; psum[o] = sm;
            }
        }
    } else {
#pragma unroll
        for (int m = 0; m < 4; ++m)
#pragma unroll
            for (int n = 0; n < 4; ++n)
#pragma unroll
                for (int r = 0; r < 4; ++r)
                    Out[(size_t)(rbase + m*16 + r) * QKVD + (cbase + n*16)] = f2bf(acc[m][n][r]);
    }
}

// stage 2: combine 64 row-chunk partials per column
__global__ void k_kstat2(const float* __restrict__ pmax, const float* __restrict__ psum,
                         float* __restrict__ kmax, float* __restrict__ ksum)
{
    int g = blockIdx.x * 64 + threadIdx.x;      // b*512 + c
    int b = g >> 9, c = g & 511;
    float m = -1e30f, s = 0.f;
    for (int rc = 0; rc < 64; ++rc) {
        float m2 = pmax[(b * 64 + rc) * 512 + c], s2 = psum[(b * 64 + rc) * 512 + c];
        float mm = fmaxf(m, m2);
        s = s * __expf(m - mm) + s2 * __expf(m2 - mm);
        m = mm;
    }
    kmax[g] = m; ksum[g] = s;
}

// ---------------- context (MFMA): 16 partial slots per (b,h).
// grid (8,8,8): block nc covers rows nc*512..+511 (4 waves x 4 iters x 32-row slabs).
// waves {2,3} reduce into {0,1} via LDS; slots nc*2+{0,1} hold the two partials.
__global__ __launch_bounds__(256, 2)
void k_ctx(const u16* __restrict__ qkv, const float* __restrict__ kmax, float* __restrict__ ctxp)
{
    __shared__ __align__(16) u16 sA[4][64 * 40];
    __shared__ __align__(16) u16 sB[4][64 * 40];
    __shared__ float scr[2][4096];
    int nc = blockIdx.x, h = blockIdx.y, b = blockIdx.z;
    int wid = threadIdx.x >> 6, lane = threadIdx.x & 63;
    u16* A  = sA[wid];
    u16* Bt = sB[wid];
    float km = kmax[b * 512 + h * 64 + lane];
    int fr = lane & 15, fk = (lane >> 4) * 8;
    f32x4 acc[4][4];
#pragma unroll
    for (int m = 0; m < 4; ++m)
#pragma unroll
        for (int n = 0; n < 4; ++n) acc[m][n] = (f32x4)0.f;

    size_t rowbase = (size_t)b * 4096 + nc * 512 + wid * 32;
    const u16* kp = qkv + rowbase * QKVD + 512 + h * 64 + lane;
    const u16* vp = kp + 512;

    for (int it = 0; it < 4; ++it) {
        const u16* kq = kp + (size_t)it * 128 * QKVD;
        const u16* vq = vp + (size_t)it * 128 * QKVD;
        unsigned int pk[16], pv[16];
#pragma unroll
        for (int j = 0; j < 16; ++j) {
            float a0 = __expf(bf2f(kq[(size_t)(2*j)   * QKVD]) - km);
            float a1 = __expf(bf2f(kq[(size_t)(2*j+1) * QKVD]) - km);
            pk[j] = (unsigned)f2bf(a0) | ((unsigned)f2bf(a1) << 16);
            float b0 = bf2f(vq[(size_t)(2*j)   * QKVD]);
            float b1 = bf2f(vq[(size_t)(2*j+1) * QKVD]);
            pv[j] = (unsigned)f2bf(b0) | ((unsigned)f2bf(b1) << 16);
        }
#pragma unroll
        for (int j = 0; j < 4; ++j) {
            *(uint4*)&A [lane * 40 + j * 8] = *(uint4*)&pk[j * 4];
            *(uint4*)&Bt[lane * 40 + j * 8] = *(uint4*)&pv[j * 4];
        }
        s16x8 af[4], bfr[4];
#pragma unroll
        for (int m = 0; m < 4; ++m) af[m]  = *(const s16x8*)&A [(m * 16 + fr) * 40 + fk];
#pragma unroll
        for (int n = 0; n < 4; ++n) bfr[n] = *(const s16x8*)&Bt[(n * 16 + fr) * 40 + fk];
#pragma unroll
        for (int m = 0; m < 4; ++m)
#pragma unroll
            for (int n = 0; n < 4; ++n)
                acc[m][n] = __builtin_amdgcn_mfma_f32_16x16x32_bf16(af[m], bfr[n], acc[m][n], 0, 0, 0);
    }

    __syncthreads();
    int rbase = (lane >> 4) * 4, cbase = lane & 15;
    if (wid >= 2) {
#pragma unroll
        for (int m = 0; m < 4; ++m)
#pragma unroll
            for (int n = 0; n < 4; ++n)
#pragma unroll
                for (int r = 0; r < 4; ++r)
                    scr[wid - 2][(m * 16 + rbase + r) * 64 + n * 16 + cbase] = acc[m][n][r];
    }
    __syncthreads();
    if (wid < 2) {
        float* cp = ctxp + (((size_t)(b * 8 + h) * 16) + nc * 2 + wid) * 4096;
#pragma unroll
        for (int m = 0; m < 4; ++m)
#pragma unroll
            for (int n = 0; n < 4; ++n)
#pragma unroll
                for (int r = 0; r < 4; ++r) {
                    int idx = (m * 16 + rbase + r) * 64 + n * 16 + cbase;
                    cp[idx] = acc[m][n][r] + scr[wid][idx];
                }
    }
}

// ---------------- Wc[b][j][h*64+d] = sum_e (ctx[b,h,d,e]/ksum[b,h,d]) * w_out[j][h*64+e]
__global__ void k_wc(const float* __restrict__ ctxp, const float* __restrict__ ksum,
                     const float* __restrict__ w_out, u16* __restrict__ Wc)
{
    __shared__ float csh[64 * 65];
    __shared__ float wsh[64 * 65];
    int jt = blockIdx.x, h = blockIdx.y, b = blockIdx.z;
    int tid = threadIdx.x;
    const float* cp = ctxp + ((size_t)(b * 8 + h) * 16) * 4096;
    for (int idx = tid; idx < 4096; idx += 256) {
        int d = idx >> 6, e = idx & 63;
        float sum = 0.f;
#pragma unroll
        for (int nc = 0; nc < 16; ++nc) sum += cp[nc * 4096 + idx];
        csh[d * 65 + e] = sum * (1.f / ksum[b * 512 + h * 64 + d]);
        wsh[d * 65 + e] = w_out[(size_t)(jt * 64 + d) * 512 + h * 64 + e];
    }
    __syncthreads();
    int j0 = (tid >> 4) * 4, d0 = (tid & 15) * 4;
    float acc[4][4] = {};
    for (int e = 0; e < 64; ++e) {
        float wv[4], cv[4];
#pragma unroll
        for (int i = 0; i < 4; ++i) wv[i] = wsh[(j0 + i) * 65 + e];
#pragma unroll
        for (int j = 0; j < 4; ++j) cv[j] = csh[(d0 + j) * 65 + e];
#pragma unroll
        for (int i = 0; i < 4; ++i)
#pragma unroll
            for (int j = 0; j < 4; ++j) acc[i][j] += wv[i] * cv[j];
    }
#pragma unroll
    for (int i = 0; i < 4; ++i)
#pragma unroll
        for (int j = 0; j < 4; ++j)
            Wc[((size_t)b * 512 + jt * 64 + j0 + i) * 512 + h * 64 + d0 + j] = f2bf(acc[i][j]);
}

// ---------------- GEMM2 + final LayerNorm fused. BM=128, BN=512 (full rows),
// BK=64, 8 waves (2Mx4N), swizzled LDS, f32 output.
__global__ __launch_bounds__(512, 1)
void k_g2ln(const u16* __restrict__ Aq, const u16* __restrict__ Wc,
            const float* __restrict__ gamma, float* __restrict__ out)
{
    __shared__ __align__(16) u16 As[128 * 64];     // 16 KB
    __shared__ __align__(16) u16 Bs[512 * 64];     // 64 KB
    __shared__ float rsum[128][4], rssq[128][4];   // 4 KB
    int bm = blockIdx.x;
    int m0 = bm * 128;
    int b = m0 >> 12;
    const u16* Bp = Wc + (size_t)b * 512 * 512;
    int tid = threadIdx.x;
    int wid = tid >> 6, lane = tid & 63;
    int wm = wid >> 2, wn = wid & 3;
    int fr = lane & 15, fc = lane >> 4;

    f32x4 acc[4][8];
#pragma unroll
    for (int m = 0; m < 4; ++m)
#pragma unroll
        for (int n = 0; n < 8; ++n) acc[m][n] = (f32x4)0.f;

    for (int k0 = 0; k0 < 512; k0 += 64) {
#pragma unroll
        for (int i = 0; i < 2; ++i) {
            int c = tid + i * 512;
            int row = c >> 3, p = c & 7, gp = swz8(row, p);
            gload_lds16(Aq + (size_t)(m0 + row) * QKVD + k0 + gp * 8, &As[c * 8]);
        }
#pragma unroll
        for (int i = 0; i < 8; ++i) {
            int c = tid + i * 512;
            int col = c >> 3, p = c & 7, gp = swz8(col, p);
            gload_lds16(Bp + (size_t)col * 512 + k0 + gp * 8, &Bs[c * 8]);
        }
        __syncthreads();
#pragma unroll
        for (int kk = 0; kk < 2; ++kk) {
            int q = kk * 4 + fc;
            s16x8 af[4], bfr[8];
#pragma unroll
            for (int m = 0; m < 4; ++m) {
                int row = wm * 64 + m * 16 + fr;
                af[m] = *(const s16x8*)&As[(row * 8 + swz8(row, q)) * 8];
            }
#pragma unroll
            for (int n = 0; n < 8; ++n) {
                int col = wn * 128 + n * 16 + fr;
                bfr[n] = *(const s16x8*)&Bs[(col * 8 + swz8(col, q)) * 8];
            }
#pragma unroll
            for (int m = 0; m < 4; ++m)
#pragma unroll
                for (int n = 0; n < 8; ++n)
                    acc[m][n] = __builtin_amdgcn_mfma_f32_16x16x32_bf16(af[m], bfr[n], acc[m][n], 0, 0, 0);
        }
        __syncthreads();
    }

    // per-row LN stats: each wave reduces its 128-col slice, cross-wave via LDS
#pragma unroll
    for (int m = 0; m < 4; ++m)
#pragma unroll
        for (int r = 0; r < 4; ++r) {
            float s = 0.f, ss = 0.f;
#pragma unroll
            for (int n = 0; n < 8; ++n) { float v = acc[m][n][r]; s += v; ss += v * v; }
#pragma unroll
            for (int d = 1; d < 16; d <<= 1) { s += __shfl_xor(s, d, 64); ss += __shfl_xor(ss, d, 64); }
            if ((lane & 15) == 0) {
                int row = wm * 64 + m * 16 + fc * 4 + r;
                rsum[row][wn] = s; rssq[row][wn] = ss;
            }
        }
    __syncthreads();

    float g[8];
#pragma unroll
    for (int n = 0; n < 8; ++n) g[n] = gamma[wn * 128 + n * 16 + fr];

#pragma unroll
    for (int m = 0; m < 4; ++m)
#pragma unroll
        for (int r = 0; r < 4; ++r) {
            int row = wm * 64 + m * 16 + fc * 4 + r;
            float s  = rsum[row][0] + rsum[row][1] + rsum[row][2] + rsum[row][3];
            float ss = rssq[row][0] + rssq[row][1] + rssq[row][2] + rssq[row][3];
            float mu = s * (1.f/512.f);
            float var = ss * (1.f/512.f) - mu * mu;
            float rs = rsqrtf(var + 1e-5f);
            float* orow = out + (size_t)(m0 + row) * 512;
#pragma unroll
            for (int n = 0; n < 8; ++n)
                orow[wn * 128 + n * 16 + fr] = (acc[m][n][r] - mu) * rs * g[n];
        }
}

extern "C" void kernel_launch(void* const* d_in, const int* in_sizes, int n_in,
                              void* d_out, int out_size, void* d_ws, size_t ws_size,
                              hipStream_t stream)
{
    const float* x        = (const float*)d_in[0];
    const float* ce       = (const float*)d_in[1];
    const float* gamma_in = (const float*)d_in[2];
    const float* w_cond   = (const float*)d_in[3];
    const float* b_cond   = (const float*)d_in[4];
    const float* w_qkv    = (const float*)d_in[5];
    const float* w_out    = (const float*)d_in[6];
    const float* gamma_out= (const float*)d_in[7];
    float* out = (float*)d_out;

    char* ws = (char*)d_ws;
    size_t o = 0;
    auto take = [&](size_t bytes) -> char* {
        char* p = ws + o; o += (bytes + 255) & ~(size_t)255; return p;
    };
    float* cond  = (float*)take(8 * 1024 * 4);
    u16*   wqkvb = (u16*)  take((size_t)1536 * 512 * 2);
    float* kmax  = (float*)take(4096 * 4);
    float* ksum  = (float*)take(4096 * 4);
    float* pmax  = (float*)take((size_t)8 * 64 * 512 * 4);
    float* psum  = (float*)take((size_t)8 * 64 * 512 * 4);
    float* ctxp  = (float*)take((size_t)64 * 16 * 4096 * 4);  // [b][h][slot16][64][64]
    u16*   Wc    = (u16*)  take((size_t)8 * 512 * 512 * 2);
    u16*   xm    = (u16*)  take((size_t)TOK * 512 * 2);
    u16*   qkv   = (u16*)  take((size_t)TOK * QKVD * 2);

    k_cond   <<<dim3(64, 8), 256, 0, stream>>>(ce, w_cond, b_cond, cond);
    k_w2bf   <<<768, 256, 0, stream>>>(w_qkv, wqkvb);
    k_lnmod  <<<8192, 256, 0, stream>>>(x, cond, gamma_in, xm);
    k_gemmqkv<<<3072, 256, 0, stream>>>(xm, wqkvb, qkv, pmax, psum);
    k_kstat2 <<<64, 64, 0, stream>>>(pmax, psum, kmax, ksum);
    k_ctx    <<<dim3(8, 8, 8), 256, 0, stream>>>(qkv, kmax, ctxp);
    k_wc     <<<dim3(8, 8, 8), 256, 0, stream>>>(ctxp, ksum, w_out, Wc);
    k_g2ln   <<<256, 512, 0, stream>>>(qkv, Wc, gamma_out, out);
}

// Round 6
// 182.478 us; speedup vs baseline: 2.0060x; 1.0402x over previous
//
#include <hip/hip_runtime.h>
#include <hip/hip_bf16.h>
#include <math.h>

typedef unsigned short u16;
typedef __attribute__((ext_vector_type(4))) float f32x4;
typedef __attribute__((ext_vector_type(8))) short s16x8;

#define B_    8
#define N_    4096
#define DIM_  512
#define TOK   32768     // B_*N_
#define QKVD  1536

__device__ __forceinline__ float bf2f(u16 u) {
    union { unsigned int i; float f; } x; x.i = ((unsigned int)u) << 16; return x.f;
}
__device__ __forceinline__ u16 f2bf(float f) {
    union { float f; unsigned int i; } x; x.f = f;
    unsigned int r = (x.i + 0x7fffu + ((x.i >> 16) & 1u)) >> 16;
    return (u16)r;
}

__device__ __forceinline__ void gload_lds16(const void* g, void* l) {
    __builtin_amdgcn_global_load_lds(
        (const __attribute__((address_space(1))) unsigned int*)g,
        (__attribute__((address_space(3))) unsigned int*)l, 16, 0, 0);
}

// 16B-chunk swizzle: LDS stays linear (gload_lds requirement); global source and
// ds_read both apply the same involution part^(row&7).
__device__ __forceinline__ int swz8(int row, int p) { return p ^ (row & 7); }

// ---------------- conditioning affine: cond[b][j] = silu(ce[b]) . w_cond[j] + b_cond[j]
__global__ void k_cond(const float* __restrict__ ce, const float* __restrict__ w_cond,
                       const float* __restrict__ b_cond, float* __restrict__ cond)
{
    __shared__ float s[512];
    int jt = blockIdx.x, b = blockIdx.y;
    int tid = threadIdx.x, wid = tid >> 6, lane = tid & 63;
    for (int i = tid; i < 512; i += 256) {
        float v = ce[b * 512 + i];
        s[i] = v / (1.f + __expf(-v));
    }
    __syncthreads();
#pragma unroll
    for (int jj = 0; jj < 4; ++jj) {
        int j = jt * 16 + wid * 4 + jj;
        const float4* w4 = (const float4*)(w_cond + (size_t)j * 512);
        float4 a = w4[lane * 2], c = w4[lane * 2 + 1];
        float acc = a.x*s[lane*8+0] + a.y*s[lane*8+1] + a.z*s[lane*8+2] + a.w*s[lane*8+3]
                  + c.x*s[lane*8+4] + c.y*s[lane*8+5] + c.z*s[lane*8+6] + c.w*s[lane*8+7];
#pragma unroll
        for (int d = 1; d < 64; d <<= 1) acc += __shfl_xor(acc, d, 64);
        if (lane == 0) cond[b * 1024 + j] = acc + b_cond[j];
    }
}

// ---------------- w_qkv fp32 -> bf16
__global__ void k_w2bf(const float* __restrict__ w, u16* __restrict__ wb)
{
    int i = (blockIdx.x * 256 + threadIdx.x) * 4;
    float4 v = *(const float4*)&w[i];
    ushort4 o; o.x = f2bf(v.x); o.y = f2bf(v.y); o.z = f2bf(v.z); o.w = f2bf(v.w);
    *(ushort4*)&wb[i] = o;
}

// ---------------- pre-LN + modulation -> xm bf16 ; one wave per token
__global__ void k_lnmod(const float* __restrict__ x, const float* __restrict__ cond,
                        const float* __restrict__ gamma, u16* __restrict__ xm)
{
    int wave = threadIdx.x >> 6, lane = threadIdx.x & 63;
    size_t t = (size_t)blockIdx.x * 4 + wave;
    const float* xr = x + t * 512;
    float4 v0 = ((const float4*)xr)[lane * 2];
    float4 v1 = ((const float4*)xr)[lane * 2 + 1];
    float s  = v0.x+v0.y+v0.z+v0.w + v1.x+v1.y+v1.z+v1.w;
    float ss = v0.x*v0.x+v0.y*v0.y+v0.z*v0.z+v0.w*v0.w
             + v1.x*v1.x+v1.y*v1.y+v1.z*v1.z+v1.w*v1.w;
#pragma unroll
    for (int m = 1; m < 64; m <<= 1) { s += __shfl_xor(s, m, 64); ss += __shfl_xor(ss, m, 64); }
    float mu = s * (1.f/512.f);
    float var = ss * (1.f/512.f) - mu * mu;
    float rs = rsqrtf(var + 1e-5f);
    int b = (int)(t >> 12);
    const float* cb = cond + b * 1024;
    float4 g0  = ((const float4*)gamma)[lane*2],     g1  = ((const float4*)gamma)[lane*2+1];
    float4 sc0 = ((const float4*)cb)[lane*2],        sc1 = ((const float4*)cb)[lane*2+1];
    float4 sh0 = ((const float4*)(cb+512))[lane*2],  sh1 = ((const float4*)(cb+512))[lane*2+1];
    ushort4 o0, o1;
    o0.x = f2bf(((v0.x-mu)*rs*g0.x)*(1.f+sc0.x) + sh0.x);
    o0.y = f2bf(((v0.y-mu)*rs*g0.y)*(1.f+sc0.y) + sh0.y);
    o0.z = f2bf(((v0.z-mu)*rs*g0.z)*(1.f+sc0.z) + sh0.z);
    o0.w = f2bf(((v0.w-mu)*rs*g0.w)*(1.f+sc0.w) + sh0.w);
    o1.x = f2bf(((v1.x-mu)*rs*g1.x)*(1.f+sc1.x) + sh1.x);
    o1.y = f2bf(((v1.y-mu)*rs*g1.y)*(1.f+sc1.y) + sh1.y);
    o1.z = f2bf(((v1.z-mu)*rs*g1.z)*(1.f+sc1.z) + sh1.z);
    o1.w = f2bf(((v1.w-mu)*rs*g1.w)*(1.f+sc1.w) + sh1.w);
    ushort4* orow = (ushort4*)(xm + t * 512);
    orow[lane * 2] = o0; orow[lane * 2 + 1] = o1;
}

// ---------------- qkv GEMM: 256x256 tile, BK=64, 8 waves, 8-phase pipelined
// schedule (counted vmcnt, double-buffered swizzled LDS, setprio around MFMA).
// Epilogue: bn<2 -> q feature-softmax (*1/8); bn in {2,3} -> k store + column
// max/sumexp partials over 128-row chunks; bn in {4,5} -> plain store (v).
__global__ __launch_bounds__(512, 1)
void k_gemmqkv(const u16* __restrict__ A,
               const u16* __restrict__ Bm,
               u16* __restrict__ Out,
               float* __restrict__ pmax, float* __restrict__ psum)
{
    __shared__ __align__(16) u16 As[2][2][128 * 64];   // [parity][half] 64 KB
    __shared__ __align__(16) u16 Bs[2][2][128 * 64];   // 64 KB
    int bid = blockIdx.x;                               // 768 blocks
    int sid = (bid & 7) * 96 + (bid >> 3);              // bijective XCD swizzle
    int bn = sid % 6, bm = sid / 6;
    int m0 = bm * 256, n0 = bn * 256;
    int tid = threadIdx.x;
    int wid = tid >> 6, lane = tid & 63;
    int wm = wid >> 2, wn = wid & 3;                    // 2M x 4N waves
    int fr = lane & 15, fc = lane >> 4;

    auto stageA = [&](int t, int h) {
        u16* dst = &As[t & 1][h][0];
        const u16* src = A + (size_t)(m0 + h * 128) * 512 + t * 64;
#pragma unroll
        for (int i = 0; i < 2; ++i) {
            int c = tid + i * 512; int row = c >> 3, p = c & 7, gp = swz8(row, p);
            gload_lds16(src + (size_t)row * 512 + gp * 8, dst + c * 8);
        }
    };
    auto stageB = [&](int t, int h) {
        u16* dst = &Bs[t & 1][h][0];
        const u16* src = Bm + (size_t)(n0 + h * 128) * 512 + t * 64;
#pragma unroll
        for (int i = 0; i < 2; ++i) {
            int c = tid + i * 512; int row = c >> 3, p = c & 7, gp = swz8(row, p);
            gload_lds16(src + (size_t)row * 512 + gp * 8, dst + c * 8);
        }
    };
    auto ldA = [&](int t, int m, int kk) -> s16x8 {
        int lr = m * 16 + fr, q = kk * 4 + fc;
        return *(const s16x8*)&As[t & 1][wm][(lr * 8 + swz8(lr, q)) * 8];
    };
    auto ldB = [&](int t, int n, int kk) -> s16x8 {
        int lr = (wn & 1) * 64 + n * 16 + fr, q = kk * 4 + fc;
        return *(const s16x8*)&Bs[t & 1][wn >> 1][(lr * 8 + swz8(lr, q)) * 8];
    };

    f32x4 acc[8][4];
#pragma unroll
    for (int m = 0; m < 8; ++m)
#pragma unroll
        for (int n = 0; n < 4; ++n) acc[m][n] = (f32x4)0.f;

    // prologue: tile 0 (A0,A1,B0,B1) + B halves of tile 1 -> 12 loads
    stageA(0, 0); stageA(0, 1); stageB(0, 0); stageB(0, 1);
    stageB(1, 0); stageB(1, 1);
    asm volatile("s_waitcnt vmcnt(4)" ::: "memory");   // tile 0 landed; B(1) may fly
    __builtin_amdgcn_s_barrier();
    __builtin_amdgcn_sched_barrier(0);

    for (int t = 0; t < 8; ++t) {
        s16x8 bb0[4], bb1[4], aa[4];
        // ---- phase 1: all B frags + A m0-3 kk0 (12 ds_reads); stage A0(t+1)
#pragma unroll
        for (int n = 0; n < 4; ++n) { bb0[n] = ldB(t, n, 0); bb1[n] = ldB(t, n, 1); }
#pragma unroll
        for (int m = 0; m < 4; ++m) aa[m] = ldA(t, m, 0);
        if (t < 7) stageA(t + 1, 0);
        __builtin_amdgcn_s_barrier();
        __builtin_amdgcn_sched_barrier(0);
        __builtin_amdgcn_s_setprio(1);
#pragma unroll
        for (int m = 0; m < 4; ++m)
#pragma unroll
            for (int n = 0; n < 4; ++n)
                acc[m][n] = __builtin_amdgcn_mfma_f32_16x16x32_bf16(aa[m], bb0[n], acc[m][n], 0, 0, 0);
        __builtin_amdgcn_s_setprio(0);
        __builtin_amdgcn_s_barrier();
        __builtin_amdgcn_sched_barrier(0);
        // ---- phase 2: A m4-7 kk0; stage A1(t+1)
#pragma unroll
        for (int m = 0; m < 4; ++m) aa[m] = ldA(t, m + 4, 0);
        if (t < 7) stageA(t + 1, 1);
        __builtin_amdgcn_s_barrier();
        __builtin_amdgcn_sched_barrier(0);
        __builtin_amdgcn_s_setprio(1);
#pragma unroll
        for (int m = 0; m < 4; ++m)
#pragma unroll
            for (int n = 0; n < 4; ++n)
                acc[m + 4][n] = __builtin_amdgcn_mfma_f32_16x16x32_bf16(aa[m], bb0[n], acc[m + 4][n], 0, 0, 0);
        __builtin_amdgcn_s_setprio(0);
        __builtin_amdgcn_s_barrier();
        __builtin_amdgcn_sched_barrier(0);
        // ---- phase 3: A m0-3 kk1; stage B0(t+2)
#pragma unroll
        for (int m = 0; m < 4; ++m) aa[m] = ldA(t, m, 1);
        if (t < 6) stageB(t + 2, 0);
        __builtin_amdgcn_s_barrier();
        __builtin_amdgcn_sched_barrier(0);
        __builtin_amdgcn_s_setprio(1);
#pragma unroll
        for (int m = 0; m < 4; ++m)
#pragma unroll
            for (int n = 0; n < 4; ++n)
                acc[m][n] = __builtin_amdgcn_mfma_f32_16x16x32_bf16(aa[m], bb1[n], acc[m][n], 0, 0, 0);
        __builtin_amdgcn_s_setprio(0);
        __builtin_amdgcn_s_barrier();
        __builtin_amdgcn_sched_barrier(0);
        // ---- phase 4: A m4-7 kk1; stage B1(t+2); counted vmcnt
#pragma unroll
        for (int m = 0; m < 4; ++m) aa[m] = ldA(t, m + 4, 1);
        if (t < 6) {
            stageB(t + 2, 1);
            asm volatile("s_waitcnt vmcnt(4)" ::: "memory");  // B(t+2) may stay in flight
        } else {
            asm volatile("s_waitcnt vmcnt(0)" ::: "memory");
        }
        __builtin_amdgcn_sched_barrier(0);
        __builtin_amdgcn_s_barrier();
        __builtin_amdgcn_sched_barrier(0);
        __builtin_amdgcn_s_setprio(1);
#pragma unroll
        for (int m = 0; m < 4; ++m)
#pragma unroll
            for (int n = 0; n < 4; ++n)
                acc[m + 4][n] = __builtin_amdgcn_mfma_f32_16x16x32_bf16(aa[m], bb1[n], acc[m + 4][n], 0, 0, 0);
        __builtin_amdgcn_s_setprio(0);
        __builtin_amdgcn_s_barrier();
        __builtin_amdgcn_sched_barrier(0);
    }

    // ---- epilogue
    int b = m0 >> 12;
    int rbase = m0 + wm * 128 + fc * 4;
    int cb = n0 + wn * 64 + fr;

    if (bn < 2) {
        // q: softmax over the wave's 64 cols (= one head), scale 1/8
#pragma unroll
        for (int m = 0; m < 8; ++m)
#pragma unroll
            for (int r = 0; r < 4; ++r) {
                float v0 = acc[m][0][r], v1 = acc[m][1][r], v2 = acc[m][2][r], v3 = acc[m][3][r];
                float mx = fmaxf(fmaxf(v0, v1), fmaxf(v2, v3));
#pragma unroll
                for (int d = 1; d < 16; d <<= 1) mx = fmaxf(mx, __shfl_xor(mx, d, 64));
                float e0 = __expf(v0 - mx), e1 = __expf(v1 - mx);
                float e2 = __expf(v2 - mx), e3 = __expf(v3 - mx);
                float sm = e0 + e1 + e2 + e3;
#pragma unroll
                for (int d = 1; d < 16; d <<= 1) sm += __shfl_xor(sm, d, 64);
                float rv = 0.125f / sm;
                size_t ro = (size_t)(rbase + m * 16 + r) * QKVD + cb;
                Out[ro]      = f2bf(e0 * rv);
                Out[ro + 16] = f2bf(e1 * rv);
                Out[ro + 32] = f2bf(e2 * rv);
                Out[ro + 48] = f2bf(e3 * rv);
            }
    } else if (bn < 4) {
        // k: store + per-wave per-column partial max/sumexp over 128 rows
        int rcc = ((m0 & 4095) >> 7) + wm;
#pragma unroll
        for (int n = 0; n < 4; ++n) {
            float vv[32]; float mx = -1e30f;
#pragma unroll
            for (int m = 0; m < 8; ++m)
#pragma unroll
                for (int r = 0; r < 4; ++r) {
                    u16 u = f2bf(acc[m][n][r]);
                    Out[(size_t)(rbase + m * 16 + r) * QKVD + cb + n * 16] = u;
                    float vf = bf2f(u);
                    vv[m * 4 + r] = vf; mx = fmaxf(mx, vf);
                }
            mx = fmaxf(mx, __shfl_xor(mx, 16, 64));
            mx = fmaxf(mx, __shfl_xor(mx, 32, 64));
            float sm = 0.f;
#pragma unroll
            for (int i = 0; i < 32; ++i) sm += __expf(vv[i] - mx);
            sm += __shfl_xor(sm, 16, 64);
            sm += __shfl_xor(sm, 32, 64);
            if (lane < 16) {
                int kcol = cb + n * 16 - 512;
                int o = (b * 32 + rcc) * 512 + kcol;
                pmax[o] = mx; psum[o] = sm;
            }
        }
    } else {
#pragma unroll
        for (int m = 0; m < 8; ++m)
#pragma unroll
            for (int n = 0; n < 4; ++n)
#pragma unroll
                for (int r = 0; r < 4; ++r)
                    Out[(size_t)(rbase + m * 16 + r) * QKVD + cb + n * 16] = f2bf(acc[m][n][r]);
    }
}

// stage 2: combine 32 row-chunk partials per column
__global__ void k_kstat2(const float* __restrict__ pmax, const float* __restrict__ psum,
                         float* __restrict__ kmax, float* __restrict__ ksum)
{
    int g = blockIdx.x * 64 + threadIdx.x;      // b*512 + c
    int b = g >> 9, c = g & 511;
    float m = -1e30f, s = 0.f;
    for (int rc = 0; rc < 32; ++rc) {
        float m2 = pmax[(b * 32 + rc) * 512 + c], s2 = psum[(b * 32 + rc) * 512 + c];
        float mm = fmaxf(m, m2);
        s = s * __expf(m - mm) + s2 * __expf(m2 - mm);
        m = mm;
    }
    kmax[g] = m; ksum[g] = s;
}

// ---------------- context (MFMA): 16 partial slots per (b,h).
// grid (8,8,8): block nc covers rows nc*512..+511 (4 waves x 4 iters x 32-row slabs).
// waves {2,3} reduce into {0,1} via LDS; slots nc*2+{0,1} hold the two partials.
__global__ __launch_bounds__(256, 2)
void k_ctx(const u16* __restrict__ qkv, const float* __restrict__ kmax, float* __restrict__ ctxp)
{
    __shared__ __align__(16) u16 sA[4][64 * 40];
    __shared__ __align__(16) u16 sB[4][64 * 40];
    __shared__ float scr[2][4096];
    int nc = blockIdx.x, h = blockIdx.y, b = blockIdx.z;
    int wid = threadIdx.x >> 6, lane = threadIdx.x & 63;
    u16* A  = sA[wid];
    u16* Bt = sB[wid];
    float km = kmax[b * 512 + h * 64 + lane];
    int fr = lane & 15, fk = (lane >> 4) * 8;
    f32x4 acc[4][4];
#pragma unroll
    for (int m = 0; m < 4; ++m)
#pragma unroll
        for (int n = 0; n < 4; ++n) acc[m][n] = (f32x4)0.f;

    size_t rowbase = (size_t)b * 4096 + nc * 512 + wid * 32;
    const u16* kp = qkv + rowbase * QKVD + 512 + h * 64 + lane;
    const u16* vp = kp + 512;

    for (int it = 0; it < 4; ++it) {
        const u16* kq = kp + (size_t)it * 128 * QKVD;
        const u16* vq = vp + (size_t)it * 128 * QKVD;
        unsigned int pk[16], pv[16];
#pragma unroll
        for (int j = 0; j < 16; ++j) {
            float a0 = __expf(bf2f(kq[(size_t)(2*j)   * QKVD]) - km);
            float a1 = __expf(bf2f(kq[(size_t)(2*j+1) * QKVD]) - km);
            pk[j] = (unsigned)f2bf(a0) | ((unsigned)f2bf(a1) << 16);
            float b0 = bf2f(vq[(size_t)(2*j)   * QKVD]);
            float b1 = bf2f(vq[(size_t)(2*j+1) * QKVD]);
            pv[j] = (unsigned)f2bf(b0) | ((unsigned)f2bf(b1) << 16);
        }
#pragma unroll
        for (int j = 0; j < 4; ++j) {
            *(uint4*)&A [lane * 40 + j * 8] = *(uint4*)&pk[j * 4];
            *(uint4*)&Bt[lane * 40 + j * 8] = *(uint4*)&pv[j * 4];
        }
        s16x8 af[4], bfr[4];
#pragma unroll
        for (int m = 0; m < 4; ++m) af[m]  = *(const s16x8*)&A [(m * 16 + fr) * 40 + fk];
#pragma unroll
        for (int n = 0; n < 4; ++n) bfr[n] = *(const s16x8*)&Bt[(n * 16 + fr) * 40 + fk];
#pragma unroll
        for (int m = 0; m < 4; ++m)
#pragma unroll
            for (int n = 0; n < 4; ++n)
                acc[m][n] = __builtin_amdgcn_mfma_f32_16x16x32_bf16(af[m], bfr[n], acc[m][n], 0, 0, 0);
    }

    __syncthreads();
    int rbase = (lane >> 4) * 4, cbase = lane & 15;
    if (wid >= 2) {
#pragma unroll
        for (int m = 0; m < 4; ++m)
#pragma unroll
            for (int n = 0; n < 4; ++n)
#pragma unroll
                for (int r = 0; r < 4; ++r)
                    scr[wid - 2][(m * 16 + rbase + r) * 64 + n * 16 + cbase] = acc[m][n][r];
    }
    __syncthreads();
    if (wid < 2) {
        float* cp = ctxp + (((size_t)(b * 8 + h) * 16) + nc * 2 + wid) * 4096;
#pragma unroll
        for (int m = 0; m < 4; ++m)
#pragma unroll
            for (int n = 0; n < 4; ++n)
#pragma unroll
                for (int r = 0; r < 4; ++r) {
                    int idx = (m * 16 + rbase + r) * 64 + n * 16 + cbase;
                    cp[idx] = acc[m][n][r] + scr[wid][idx];
                }
    }
}

// ---------------- Wc[b][j][h*64+d] = sum_e (ctx[b,h,d,e]/ksum[b,h,d]) * w_out[j][h*64+e]
__global__ void k_wc(const float* __restrict__ ctxp, const float* __restrict__ ksum,
                     const float* __restrict__ w_out, u16* __restrict__ Wc)
{
    __shared__ float csh[64 * 65];
    __shared__ float wsh[64 * 65];
    int jt = blockIdx.x, h = blockIdx.y, b = blockIdx.z;
    int tid = threadIdx.x;
    const float* cp = ctxp + ((size_t)(b * 8 + h) * 16) * 4096;
    for (int idx = tid; idx < 4096; idx += 256) {
        int d = idx >> 6, e = idx & 63;
        float sum = 0.f;
#pragma unroll
        for (int nc = 0; nc < 16; ++nc) sum += cp[nc * 4096 + idx];
        csh[d * 65 + e] = sum * (1.f / ksum[b * 512 + h * 64 + d]);
        wsh[d * 65 + e] = w_out[(size_t)(jt * 64 + d) * 512 + h * 64 + e];
    }
    __syncthreads();
    int j0 = (tid >> 4) * 4, d0 = (tid & 15) * 4;
    float acc[4][4] = {};
    for (int e = 0; e < 64; ++e) {
        float wv[4], cv[4];
#pragma unroll
        for (int i = 0; i < 4; ++i) wv[i] = wsh[(j0 + i) * 65 + e];
#pragma unroll
        for (int j = 0; j < 4; ++j) cv[j] = csh[(d0 + j) * 65 + e];
#pragma unroll
        for (int i = 0; i < 4; ++i)
#pragma unroll
            for (int j = 0; j < 4; ++j) acc[i][j] += wv[i] * cv[j];
    }
#pragma unroll
    for (int i = 0; i < 4; ++i)
#pragma unroll
        for (int j = 0; j < 4; ++j)
            Wc[((size_t)b * 512 + jt * 64 + j0 + i) * 512 + h * 64 + d0 + j] = f2bf(acc[i][j]);
}

// ---------------- GEMM2 + final LayerNorm fused. BM=128, BN=512 (full rows),
// BK=64, 8 waves (2Mx4N), swizzled LDS, f32 output.
__global__ __launch_bounds__(512, 1)
void k_g2ln(const u16* __restrict__ Aq, const u16* __restrict__ Wc,
            const float* __restrict__ gamma, float* __restrict__ out)
{
    __shared__ __align__(16) u16 As[128 * 64];     // 16 KB
    __shared__ __align__(16) u16 Bs[512 * 64];     // 64 KB
    __shared__ float rsum[128][4], rssq[128][4];   // 4 KB
    int bm = blockIdx.x;
    int m0 = bm * 128;
    int b = m0 >> 12;
    const u16* Bp = Wc + (size_t)b * 512 * 512;
    int tid = threadIdx.x;
    int wid = tid >> 6, lane = tid & 63;
    int wm = wid >> 2, wn = wid & 3;
    int fr = lane & 15, fc = lane >> 4;

    f32x4 acc[4][8];
#pragma unroll
    for (int m = 0; m < 4; ++m)
#pragma unroll
        for (int n = 0; n < 8; ++n) acc[m][n] = (f32x4)0.f;

    for (int k0 = 0; k0 < 512; k0 += 64) {
#pragma unroll
        for (int i = 0; i < 2; ++i) {
            int c = tid + i * 512;
            int row = c >> 3, p = c & 7, gp = swz8(row, p);
            gload_lds16(Aq + (size_t)(m0 + row) * QKVD + k0 + gp * 8, &As[c * 8]);
        }
#pragma unroll
        for (int i = 0; i < 8; ++i) {
            int c = tid + i * 512;
            int col = c >> 3, p = c & 7, gp = swz8(col, p);
            gload_lds16(Bp + (size_t)col * 512 + k0 + gp * 8, &Bs[c * 8]);
        }
        __syncthreads();
#pragma unroll
        for (int kk = 0; kk < 2; ++kk) {
            int q = kk * 4 + fc;
            s16x8 af[4], bfr[8];
#pragma unroll
            for (int m = 0; m < 4; ++m) {
                int row = wm * 64 + m * 16 + fr;
                af[m] = *(const s16x8*)&As[(row * 8 + swz8(row, q)) * 8];
            }
#pragma unroll
            for (int n = 0; n < 8; ++n) {
                int col = wn * 128 + n * 16 + fr;
                bfr[n] = *(const s16x8*)&Bs[(col * 8 + swz8(col, q)) * 8];
            }
#pragma unroll
            for (int m = 0; m < 4; ++m)
#pragma unroll
                for (int n = 0; n < 8; ++n)
                    acc[m][n] = __builtin_amdgcn_mfma_f32_16x16x32_bf16(af[m], bfr[n], acc[m][n], 0, 0, 0);
        }
        __syncthreads();
    }

    // per-row LN stats: each wave reduces its 128-col slice, cross-wave via LDS
#pragma unroll
    for (int m = 0; m < 4; ++m)
#pragma unroll
        for (int r = 0; r < 4; ++r) {
            float s = 0.f, ss = 0.f;
#pragma unroll
            for (int n = 0; n < 8; ++n) { float v = acc[m][n][r]; s += v; ss += v * v; }
#pragma unroll
            for (int d = 1; d < 16; d <<= 1) { s += __shfl_xor(s, d, 64); ss += __shfl_xor(ss, d, 64); }
            if ((lane & 15) == 0) {
                int row = wm * 64 + m * 16 + fc * 4 + r;
                rsum[row][wn] = s; rssq[row][wn] = ss;
            }
        }
    __syncthreads();

    float g[8];
#pragma unroll
    for (int n = 0; n < 8; ++n) g[n] = gamma[wn * 128 + n * 16 + fr];

#pragma unroll
    for (int m = 0; m < 4; ++m)
#pragma unroll
        for (int r = 0; r < 4; ++r) {
            int row = wm * 64 + m * 16 + fc * 4 + r;
            float s  = rsum[row][0] + rsum[row][1] + rsum[row][2] + rsum[row][3];
            float ss = rssq[row][0] + rssq[row][1] + rssq[row][2] + rssq[row][3];
            float mu = s * (1.f/512.f);
            float var = ss * (1.f/512.f) - mu * mu;
            float rs = rsqrtf(var + 1e-5f);
            float* orow = out + (size_t)(m0 + row) * 512;
#pragma unroll
            for (int n = 0; n < 8; ++n)
                orow[wn * 128 + n * 16 + fr] = (acc[m][n][r] - mu) * rs * g[n];
        }
}

extern "C" void kernel_launch(void* const* d_in, const int* in_sizes, int n_in,
                              void* d_out, int out_size, void* d_ws, size_t ws_size,
                              hipStream_t stream)
{
    const float* x        = (const float*)d_in[0];
    const float* ce       = (const float*)d_in[1];
    const float* gamma_in = (const float*)d_in[2];
    const float* w_cond   = (const float*)d_in[3];
    const float* b_cond   = (const float*)d_in[4];
    const float* w_qkv    = (const float*)d_in[5];
    const float* w_out    = (const float*)d_in[6];
    const float* gamma_out= (const float*)d_in[7];
    float* out = (float*)d_out;

    char* ws = (char*)d_ws;
    size_t o = 0;
    auto take = [&](size_t bytes) -> char* {
        char* p = ws + o; o += (bytes + 255) & ~(size_t)255; return p;
    };
    float* cond  = (float*)take(8 * 1024 * 4);
    u16*   wqkvb = (u16*)  take((size_t)1536 * 512 * 2);
    float* kmax  = (float*)take(4096 * 4);
    float* ksum  = (float*)take(4096 * 4);
    float* pmax  = (float*)take((size_t)8 * 32 * 512 * 4);
    float* psum  = (float*)take((size_t)8 * 32 * 512 * 4);
    float* ctxp  = (float*)take((size_t)64 * 16 * 4096 * 4);  // [b][h][slot16][64][64]
    u16*   Wc    = (u16*)  take((size_t)8 * 512 * 512 * 2);
    u16*   xm    = (u16*)  take((size_t)TOK * 512 * 2);
    u16*   qkv   = (u16*)  take((size_t)TOK * QKVD * 2);

    k_cond   <<<dim3(64, 8), 256, 0, stream>>>(ce, w_cond, b_cond, cond);
    k_w2bf   <<<768, 256, 0, stream>>>(w_qkv, wqkvb);
    k_lnmod  <<<8192, 256, 0, stream>>>(x, cond, gamma_in, xm);
    k_gemmqkv<<<768, 512, 0, stream>>>(xm, wqkvb, qkv, pmax, psum);
    k_kstat2 <<<64, 64, 0, stream>>>(pmax, psum, kmax, ksum);
    k_ctx    <<<dim3(8, 8, 8), 256, 0, stream>>>(qkv, kmax, ctxp);
    k_wc     <<<dim3(8, 8, 8), 256, 0, stream>>>(ctxp, ksum, w_out, Wc);
    k_g2ln   <<<256, 512, 0, stream>>>(qkv, Wc, gamma_out, out);
}